// Round 5
// baseline (4995.976 us; speedup 1.0000x reference)
//
#include <hip/hip_runtime.h>
#include <hip/hip_bf16.h>
#include <math.h>

// ---------------------------------------------------------------------------
// GIN + JumpingKnowledge(cat) + mean-pool + 2-layer head, eval mode.
// R21 (on R19, 518us; R20's 64-node/8-deep variant REGRESSED 567us and is
// reverted): edge-parallel aggregation inside the fused layer kernel.
//  - col[] now packs (dst&127)<<24 | src at CSC build (blocks are 128-
//    aligned so local dst = dst&127; src<2^24).
//  - agg phase: init z rows = (1+eps)*h[bb+row] (sequential, coalesced),
//    barrier, then ALL 512 threads walk the block's contiguous edge range
//    [rp[bb], rp[bb+128]) uniformly: 8 threads/edge x 64 edge-slots,
//    ds_add_f32 into sbuf z rows. Replaces the node-parallel scheme whose
//    wave ran at the max of 8 Poisson(8) slot-counts (~75% wasted issue).
//  - accumulate moves VALU-fma -> idle LDS-atomic pipe; balance perfect;
//    col reads coalesced; no masked gathers.
// Keeps: R19 fusion (z in sbuf f32 -> MFMA MLP -> pool), 512thr/128 nodes,
// R15/R16 build/z0/split-bf16 MFMA/pool/final.
// ---------------------------------------------------------------------------

typedef unsigned int uint;
typedef unsigned short ushort;
typedef __attribute__((ext_vector_type(8))) short short8;
typedef __attribute__((ext_vector_type(4))) float floatx4;
typedef __attribute__((ext_vector_type(4))) uint uintx4;

#define BBITS 10                 // 1024 nodes per bucket
#define BCAP 20480               // arena capacity per bucket
#define BMASK ((1 << BBITS) - 1)

__device__ __forceinline__ float bf_lo(uint w) { return __uint_as_float(w << 16); }
__device__ __forceinline__ float bf_hi(uint w) { return __uint_as_float(w & 0xffff0000u); }

__device__ __forceinline__ ushort f2bf(float x) {
  __hip_bfloat16 h = __float2bfloat16(x);
  return *(ushort*)&h;
}
__device__ __forceinline__ float bf2f(ushort u) { return __uint_as_float((uint)u << 16); }

__device__ __forceinline__ uint pack_bf16(float a, float b) {
  return (uint)f2bf(a) | ((uint)f2bf(b) << 16);
}

__device__ __forceinline__ void split8(float4 u0, float4 u1, short8& hi, short8& lo) {
  float v0 = u0.x, v1 = u0.y, v2 = u0.z, v3 = u0.w;
  float v4 = u1.x, v5 = u1.y, v6 = u1.z, v7 = u1.w;
  ushort h0 = f2bf(v0), h1 = f2bf(v1), h2 = f2bf(v2), h3 = f2bf(v3);
  ushort h4 = f2bf(v4), h5 = f2bf(v5), h6 = f2bf(v6), h7 = f2bf(v7);
  hi[0] = (short)h0; hi[1] = (short)h1; hi[2] = (short)h2; hi[3] = (short)h3;
  hi[4] = (short)h4; hi[5] = (short)h5; hi[6] = (short)h6; hi[7] = (short)h7;
  lo[0] = (short)f2bf(v0 - bf2f(h0)); lo[1] = (short)f2bf(v1 - bf2f(h1));
  lo[2] = (short)f2bf(v2 - bf2f(h2)); lo[3] = (short)f2bf(v3 - bf2f(h3));
  lo[4] = (short)f2bf(v4 - bf2f(h4)); lo[5] = (short)f2bf(v5 - bf2f(h5));
  lo[6] = (short)f2bf(v6 - bf2f(h6)); lo[7] = (short)f2bf(v7 - bf2f(h7));
}

__device__ __forceinline__ short8 hi8(float4 u0, float4 u1) {
  short8 h;
  h[0] = (short)f2bf(u0.x); h[1] = (short)f2bf(u0.y);
  h[2] = (short)f2bf(u0.z); h[3] = (short)f2bf(u0.w);
  h[4] = (short)f2bf(u1.x); h[5] = (short)f2bf(u1.y);
  h[6] = (short)f2bf(u1.z); h[7] = (short)f2bf(u1.w);
  return h;
}

// ---- atomic-free binned CSC build (packed arena) ---------------------------

__global__ void init_bc_kernel(int* __restrict__ bc, int NB) {
  int b = threadIdx.x;
  if (b < NB) bc[b * 16] = b * BCAP;
}

__global__ __launch_bounds__(1024) void bin_edges_kernel(
    const int* __restrict__ src, const int* __restrict__ dst, int* __restrict__ bc,
    uint* __restrict__ arena, int E) {
  __shared__ int cnt[128], base[128];
  for (long chunk = (long)blockIdx.x * 4096; chunk < E; chunk += (long)gridDim.x * 4096) {
    if (threadIdx.x < 128) cnt[threadIdx.x] = 0;
    __syncthreads();
    uint v[4];
    int b[4], r[4];
#pragma unroll
    for (int u = 0; u < 4; ++u) {
      long e = chunk + threadIdx.x + u * 1024;
      if (e < E) {
        int s = src[e];
        int d = dst[e];
        b[u] = d >> BBITS;
        v[u] = ((uint)s << BBITS) | (uint)(d & BMASK);
        r[u] = atomicAdd(&cnt[b[u]], 1);
      }
    }
    __syncthreads();
    if (threadIdx.x < 128)
      base[threadIdx.x] = cnt[threadIdx.x] ? atomicAdd(&bc[threadIdx.x * 16], cnt[threadIdx.x]) : 0;
    __syncthreads();
#pragma unroll
    for (int u = 0; u < 4; ++u) {
      long e = chunk + threadIdx.x + u * 1024;
      if (e < E) arena[base[b[u]] + r[u]] = v[u];
    }
    __syncthreads();
  }
}

__global__ __launch_bounds__(1024) void bucket_count_kernel(
    const uint* __restrict__ arena, const int* __restrict__ bc,
    int* __restrict__ deg, int N) {
  __shared__ int hist[1 << BBITS];
  int b = blockIdx.x;
  int lo = b << BBITS;
  int hi = min(lo + (1 << BBITS), N);
  hist[threadIdx.x] = 0;
  __syncthreads();
  int cnt = bc[b * 16] - b * BCAP;
  const uint* ad = arena + (size_t)b * BCAP;
  for (int i = threadIdx.x; i < cnt; i += 1024) atomicAdd(&hist[ad[i] & BMASK], 1);
  __syncthreads();
  if (lo + (int)threadIdx.x < hi) deg[lo + threadIdx.x] = hist[threadIdx.x];
}

// col[pos] = (dst&127)<<24 | src   (src < 2^24; 128-node-aligned blocks)
__global__ __launch_bounds__(1024) void bucket_scatter_kernel(
    const uint* __restrict__ arena, const int* __restrict__ bc,
    const int* __restrict__ rp, int* __restrict__ col, int N) {
  __shared__ int cur[1 << BBITS];
  int b = blockIdx.x;
  int lo = b << BBITS;
  int hi = min(lo + (1 << BBITS), N);
  if (lo + (int)threadIdx.x < hi) cur[threadIdx.x] = rp[lo + threadIdx.x];
  __syncthreads();
  int cnt = bc[b * 16] - b * BCAP;
  const uint* ad = arena + (size_t)b * BCAP;
  for (int i = threadIdx.x; i < cnt; i += 1024) {
    uint v = ad[i];
    int pos = atomicAdd(&cur[v & BMASK], 1);
    col[pos] = (int)(((v & 127u) << 24) | (v >> BBITS));
  }
}

// ---- scan -----------------------------------------------------------------
__global__ void scan_blocksums(const int* __restrict__ deg, int* __restrict__ bsum, int N) {
  __shared__ int red[256];
  int i = blockIdx.x * 256 + threadIdx.x;
  red[threadIdx.x] = (i < N) ? deg[i] : 0;
  __syncthreads();
  for (int off = 128; off > 0; off >>= 1) {
    if (threadIdx.x < off) red[threadIdx.x] += red[threadIdx.x + off];
    __syncthreads();
  }
  if (threadIdx.x == 0) bsum[blockIdx.x] = red[0];
}

__global__ void scan_bsum(const int* __restrict__ bsum, int* __restrict__ boff,
                          int* __restrict__ rp_last, int B) {
  __shared__ int tmp[1024];
  int t = threadIdx.x;
  int v = (t < B) ? bsum[t] : 0;
  tmp[t] = v;
  __syncthreads();
  for (int off = 1; off < 1024; off <<= 1) {
    int u = (t >= off) ? tmp[t - off] : 0;
    __syncthreads();
    tmp[t] += u;
    __syncthreads();
  }
  if (t < B) boff[t] = tmp[t] - v;
  if (t == 1023) *rp_last = tmp[1023];
}

__global__ void scan_final(const int* __restrict__ deg, const int* __restrict__ boff,
                           int* __restrict__ rp, int N) {
  __shared__ int tmp[256];
  int i = blockIdx.x * 256 + threadIdx.x;
  int v = (i < N) ? deg[i] : 0;
  tmp[threadIdx.x] = v;
  __syncthreads();
  for (int off = 1; off < 256; off <<= 1) {
    int u = (threadIdx.x >= off) ? tmp[threadIdx.x - off] : 0;
    __syncthreads();
    tmp[threadIdx.x] += u;
    __syncthreads();
  }
  if (i < N) rp[i] = boff[blockIdx.x] + tmp[threadIdx.x] - v;
}

__global__ void graph_bounds_kernel(const int* __restrict__ batch, int* __restrict__ gs,
                                    int N, int G) {
  int n = blockIdx.x * 256 + threadIdx.x;
  if (n >= N) return;
  int b = batch[n];
  int bp = (n == 0) ? -1 : batch[n - 1];
  for (int g = bp + 1; g <= b; ++g) gs[g] = n;
  if (n == N - 1)
    for (int g = b + 1; g <= G; ++g) gs[g] = N;
}

// Prepack W1/W2 into MFMA B-fragment order, split hi/lo bf16.
__global__ void prepack_w_kernel(const float* __restrict__ W1_rest,
                                 const float* __restrict__ W2, ushort* __restrict__ wp) {
  int l = blockIdx.x >> 1, g = blockIdx.x & 1;
  const float* W;
  if (g == 0) {
    if (l == 0) return;
    W = W1_rest + (size_t)(l - 1) * 4096;
  } else {
    W = W2 + (size_t)l * 4096;
  }
  ushort* out = wp + (size_t)(l * 2 + g) * 8192;
  for (int idx = threadIdx.x; idx < 4096; idx += blockDim.x) {
    int j = idx & 7, lane = (idx >> 3) & 63, ks = (idx >> 9) & 1, nt = (idx >> 10) & 3;
    int k = ks * 32 + (lane >> 4) * 8 + j;
    int n = nt * 16 + (lane & 15);
    float w = W[k * 64 + n];
    ushort hi = f2bf(w);
    ushort lo = f2bf(w - bf2f(hi));
    size_t base = (size_t)((nt * 2 + ks) * 2) * 512 + lane * 8 + j;
    out[base] = hi;
    out[base + 512] = lo;
  }
}

// ---------------------------------------------------------------------------
// Fused GIN layer: edge-parallel agg (z in sbuf, f32, LDS atomics) +
// MFMA MLP + mean-pool. 128 nodes/block, 512 threads.
// ---------------------------------------------------------------------------
__global__ __launch_bounds__(512) void fused_layer_kernel(
    const ushort* __restrict__ hb, const float* __restrict__ z0,
    const float* __restrict__ W1f, ushort* __restrict__ hout,
    const int* __restrict__ rp, const int* __restrict__ col,
    const float* __restrict__ eps,
    const ushort* __restrict__ wp1, const ushort* __restrict__ wp2,
    const float* __restrict__ b1, const float* __restrict__ g1,
    const float* __restrict__ be1, const float* __restrict__ m1,
    const float* __restrict__ v1,
    const float* __restrict__ b2, const float* __restrict__ g2,
    const float* __restrict__ be2, const float* __restrict__ m2,
    const float* __restrict__ v2,
    const int* __restrict__ batch, float* __restrict__ pooled,
    int layer, int skip1, int N) {
  __shared__ float bnp[6][64];
  __shared__ float w1fl[64];
  __shared__ float sbuf[128][68];  // phase0: z rows; phase1: t rows; epilogue: h
  __shared__ int batchl[128];
  int tid = threadIdx.x;
  int blockbase = blockIdx.x * 128;
  if (tid < 64) {
    bnp[0][tid] = b1[tid];
    float s1 = g1[tid] * rsqrtf(v1[tid] + 1e-5f);
    bnp[1][tid] = s1;
    bnp[2][tid] = be1[tid] - m1[tid] * s1;
    bnp[3][tid] = b2[tid];
    float s2 = g2[tid] * rsqrtf(v2[tid] + 1e-5f);
    bnp[4][tid] = s2;
    bnp[5][tid] = be2[tid] - m2[tid] * s2;
    if (skip1) w1fl[tid] = W1f[tid];
  }
  if (tid < 128) batchl[tid] = (blockbase + tid < N) ? batch[blockbase + tid] : -1;
  int wave = tid >> 6, lane = tid & 63;
  int q = lane >> 4, c = lane & 15;
  int base = blockbase + wave * 16;
  int srow = wave * 16;  // this wave's strip base row in sbuf

  short8 ahi0, alo0, ahi1, alo1;
  if (!skip1) {
    // ---- phase 0a: init z rows = (1+eps)*h[node]  (coalesced, 2/thread)
    float ep = 1.0f + eps[layer];
#pragma unroll
    for (int it = 0; it < 2; ++it) {
      int chunk = tid + it * 512;
      int row = chunk >> 3, c8 = chunk & 7;
      long nn = blockbase + row;
      if (nn >= N) nn = N - 1;
      uint4 hv = ((const uint4*)(hb + nn * 64))[c8];
      *(float4*)&sbuf[row][c8 * 8] =
          make_float4(ep * bf_lo(hv.x), ep * bf_hi(hv.x), ep * bf_lo(hv.y), ep * bf_hi(hv.y));
      *(float4*)&sbuf[row][c8 * 8 + 4] =
          make_float4(ep * bf_lo(hv.z), ep * bf_hi(hv.z), ep * bf_lo(hv.w), ep * bf_hi(hv.w));
    }
    __syncthreads();
    // ---- phase 0b: edge-parallel accumulate. 8 threads/edge x 64 slots.
    {
      int nhi = blockbase + 128;
      if (nhi > N) nhi = N;
      int ebeg = rp[blockbase];
      int eend = rp[nhi];
      int el = tid >> 3;   // edge slot 0..63
      int r = tid & 7;     // 16B chunk
      for (int e0 = ebeg + el; e0 < eend; e0 += 64 * 4) {
        int ev[4];
        bool ok[4];
#pragma unroll
        for (int k = 0; k < 4; ++k) {
          int ec = e0 + 64 * k;
          ok[k] = ec < eend;
          ev[k] = __builtin_nontemporal_load(col + (ok[k] ? ec : e0));
        }
        uint4 ww[4];
#pragma unroll
        for (int k = 0; k < 4; ++k) {
          long src = (long)(ev[k] & 0xFFFFFF);
          ww[k] = ((const uint4*)(hb + src * 64))[r];
        }
#pragma unroll
        for (int k = 0; k < 4; ++k) {
          if (ok[k]) {
            float* rowp = &sbuf[(ev[k] >> 24) & 127][r * 8];
            atomicAdd(rowp + 0, bf_lo(ww[k].x));
            atomicAdd(rowp + 1, bf_hi(ww[k].x));
            atomicAdd(rowp + 2, bf_lo(ww[k].y));
            atomicAdd(rowp + 3, bf_hi(ww[k].y));
            atomicAdd(rowp + 4, bf_lo(ww[k].z));
            atomicAdd(rowp + 5, bf_hi(ww[k].z));
            atomicAdd(rowp + 6, bf_lo(ww[k].w));
            atomicAdd(rowp + 7, bf_hi(ww[k].w));
          }
        }
      }
    }
    __syncthreads();
    // ---- A-fragments from sbuf z rows
    {
      float4 u0 = *(const float4*)&sbuf[srow + c][q * 8];
      float4 u1 = *(const float4*)&sbuf[srow + c][q * 8 + 4];
      ahi0 = hi8(u0, u1);
      u0 = *(const float4*)&sbuf[srow + c][32 + q * 8];
      u1 = *(const float4*)&sbuf[srow + c][32 + q * 8 + 4];
      ahi1 = hi8(u0, u1);
    }
    floatx4 acc[4];
#pragma unroll
    for (int nt = 0; nt < 4; ++nt) acc[nt] = (floatx4){0.f, 0.f, 0.f, 0.f};
#pragma unroll
    for (int nt = 0; nt < 4; ++nt) {
#pragma unroll
      for (int ks = 0; ks < 2; ++ks) {
        const ushort* fb = wp1 + ((nt * 2 + ks) * 2) * 512 + lane * 8;
        short8 bh = *(const short8*)fb;
        short8 bl = *(const short8*)(fb + 512);
        short8 ah = ks ? ahi1 : ahi0;
        acc[nt] = __builtin_amdgcn_mfma_f32_16x16x32_bf16(ah, bh, acc[nt], 0, 0, 0);
        acc[nt] = __builtin_amdgcn_mfma_f32_16x16x32_bf16(ah, bl, acc[nt], 0, 0, 0);
      }
    }
    // bn1 -> t rows (wave-local strip; same-wave in-order LDS)
    __syncthreads();
#pragma unroll
    for (int nt = 0; nt < 4; ++nt) {
      int feat = nt * 16 + c;
      float s1 = bnp[1][feat], o1 = bnp[2][feat], bb = bnp[0][feat];
#pragma unroll
      for (int r2 = 0; r2 < 4; ++r2) {
        float y = fmaxf(acc[nt][r2] + bb, 0.f);
        sbuf[srow + q * 4 + r2][feat] = fmaf(y, s1, o1);
      }
    }
    float4 u0 = *(const float4*)&sbuf[srow + c][q * 8];
    float4 u1 = *(const float4*)&sbuf[srow + c][q * 8 + 4];
    split8(u0, u1, ahi0, alo0);
    u0 = *(const float4*)&sbuf[srow + c][32 + q * 8];
    u1 = *(const float4*)&sbuf[srow + c][32 + q * 8 + 4];
    split8(u0, u1, ahi1, alo1);
  } else {
    __syncthreads();
    long row = base + c;
    if (row >= N) row = N - 1;
    float zv = z0[row];
    float4 t00, t01, t10, t11;
    {
      float tv[8];
#pragma unroll
      for (int j = 0; j < 8; ++j) {
        int k = q * 8 + j;
        float y = fmaxf(fmaf(zv, w1fl[k], bnp[0][k]), 0.f);
        tv[j] = fmaf(y, bnp[1][k], bnp[2][k]);
      }
      t00 = make_float4(tv[0], tv[1], tv[2], tv[3]);
      t01 = make_float4(tv[4], tv[5], tv[6], tv[7]);
#pragma unroll
      for (int j = 0; j < 8; ++j) {
        int k = 32 + q * 8 + j;
        float y = fmaxf(fmaf(zv, w1fl[k], bnp[0][k]), 0.f);
        tv[j] = fmaf(y, bnp[1][k], bnp[2][k]);
      }
      t10 = make_float4(tv[0], tv[1], tv[2], tv[3]);
      t11 = make_float4(tv[4], tv[5], tv[6], tv[7]);
    }
    split8(t00, t01, ahi0, alo0);
    split8(t10, t11, ahi1, alo1);
  }

  // GEMM2: 3-term
  floatx4 acc2[4];
#pragma unroll
  for (int nt = 0; nt < 4; ++nt) acc2[nt] = (floatx4){0.f, 0.f, 0.f, 0.f};
#pragma unroll
  for (int nt = 0; nt < 4; ++nt) {
#pragma unroll
    for (int ks = 0; ks < 2; ++ks) {
      const ushort* fb = wp2 + ((nt * 2 + ks) * 2) * 512 + lane * 8;
      short8 bh = *(const short8*)fb;
      short8 bl = *(const short8*)(fb + 512);
      short8 ah = ks ? ahi1 : ahi0;
      short8 al = ks ? alo1 : alo0;
      acc2[nt] = __builtin_amdgcn_mfma_f32_16x16x32_bf16(ah, bh, acc2[nt], 0, 0, 0);
      acc2[nt] = __builtin_amdgcn_mfma_f32_16x16x32_bf16(al, bh, acc2[nt], 0, 0, 0);
      acc2[nt] = __builtin_amdgcn_mfma_f32_16x16x32_bf16(ah, bl, acc2[nt], 0, 0, 0);
    }
  }

  // bn2 -> stage vals in sbuf (wave-local rows)
#pragma unroll
  for (int nt = 0; nt < 4; ++nt) {
    int feat = nt * 16 + c;
    float s2 = bnp[4][feat], o2 = bnp[5][feat], bb = bnp[3][feat];
#pragma unroll
    for (int r2 = 0; r2 < 4; ++r2) {
      int node = base + q * 4 + r2;
      float val = 0.f;
      if (node < N) {
        float y = fmaxf(acc2[nt][r2] + bb, 0.f);
        val = fmaf(y, s2, o2);
      }
      sbuf[srow + q * 4 + r2][feat] = val;
    }
  }
  __syncthreads();

  // vectorized h stores: 128 rows x 8 chunks of 16B; 2 chunks/thread
#pragma unroll
  for (int it = 0; it < 2; ++it) {
    int chunk = tid + it * 512;
    int row = chunk >> 3, c8 = chunk & 7;
    int node = blockbase + row;
    if (node < N) {
      const float* sp = &sbuf[row][c8 * 8];
      uintx4 w;
      w.x = pack_bf16(sp[0], sp[1]);
      w.y = pack_bf16(sp[2], sp[3]);
      w.z = pack_bf16(sp[4], sp[5]);
      w.w = pack_bf16(sp[6], sp[7]);
      *(uintx4*)(hout + (long)node * 64 + c8 * 8) = w;
    }
  }

  // parallel segment sums: 256 threads = feat(64) x quarter(4), 32 rows each
  if (tid < 256) {
    int j = tid & 63;
    int quarter = tid >> 6;
    int nvalid = N - blockbase;
    if (nvalid > 128) nvalid = 128;
    int i = quarter * 32;
    int iend = i + 32;
    if (iend > nvalid) iend = nvalid;
    while (i < iend) {
      int g = batchl[i];
      float s = 0.f;
      while (i < iend && batchl[i] == g) { s += sbuf[i][j]; ++i; }
      atomicAdd(&pooled[(size_t)g * 512 + layer * 64 + j], s);
    }
  }
}

__global__ void z0_kernel(const float* __restrict__ x, const int* __restrict__ rp,
                          const int* __restrict__ col, const float* __restrict__ eps,
                          float* __restrict__ z0, int N) {
  int n = blockIdx.x * blockDim.x + threadIdx.x;
  if (n >= N) return;
  int beg = rp[n], end = rp[n + 1];
  float a = 0.f;
  for (int e = beg; e < end; ++e) a += x[col[e] & 0xFFFFFF];
  z0[n] = fmaf(1.0f + eps[0], x[n], a);
}

__global__ __launch_bounds__(64) void final_kernel(
    const float* __restrict__ pooled, const int* __restrict__ gs,
    const float* __restrict__ lin1_w, const float* __restrict__ lin1_b,
    const float* __restrict__ lin2_w, const float* __restrict__ lin2_b,
    float* __restrict__ out, int G) {
  int g = blockIdx.x;
  int j = threadIdx.x;
  float inv = 1.0f / fmaxf((float)(gs[g + 1] - gs[g]), 1.0f);
  __shared__ float p[512];
  for (int t = j; t < 512; t += 64) p[t] = pooled[(long)g * 512 + t] * inv;
  __syncthreads();
  float a0 = lin1_b[j], a1 = 0.f, a2 = 0.f, a3 = 0.f;
  for (int k = 0; k < 512; k += 4) {
    a0 = fmaf(p[k + 0], lin1_w[(k + 0) * 64 + j], a0);
    a1 = fmaf(p[k + 1], lin1_w[(k + 1) * 64 + j], a1);
    a2 = fmaf(p[k + 2], lin1_w[(k + 2) * 64 + j], a2);
    a3 = fmaf(p[k + 3], lin1_w[(k + 3) * 64 + j], a3);
  }
  float hv = fmaxf((a0 + a1) + (a2 + a3), 0.f);
  __shared__ float hb[64];
  hb[j] = hv;
  __syncthreads();
  __shared__ float lg[3];
  if (j < 3) {
    float a = lin2_b[j];
#pragma unroll
    for (int k = 0; k < 64; ++k) a = fmaf(hb[k], lin2_w[k * 3 + j], a);
    lg[j] = a;
  }
  __syncthreads();
  if (j < 3) {
    float mx = fmaxf(fmaxf(lg[0], lg[1]), lg[2]);
    float lse = mx + logf(expf(lg[0] - mx) + expf(lg[1] - mx) + expf(lg[2] - mx));
    out[g * 3 + j] = lg[j] - lse;
  }
}

extern "C" void kernel_launch(void* const* d_in, const int* in_sizes, int n_in,
                              void* d_out, int out_size, void* d_ws, size_t ws_size,
                              hipStream_t stream) {
  const float* x        = (const float*)d_in[0];
  const int*   edge     = (const int*)d_in[1];
  const int*   batch    = (const int*)d_in[2];
  const float* eps      = (const float*)d_in[4];
  const float* W1_first = (const float*)d_in[5];
  const float* W1_rest  = (const float*)d_in[6];
  const float* b1       = (const float*)d_in[7];
  const float* g1       = (const float*)d_in[8];
  const float* be1      = (const float*)d_in[9];
  const float* m1       = (const float*)d_in[10];
  const float* v1       = (const float*)d_in[11];
  const float* W2       = (const float*)d_in[12];
  const float* b2       = (const float*)d_in[13];
  const float* g2       = (const float*)d_in[14];
  const float* be2      = (const float*)d_in[15];
  const float* m2       = (const float*)d_in[16];
  const float* v2       = (const float*)d_in[17];
  const float* lin1_w   = (const float*)d_in[18];
  const float* lin1_b   = (const float*)d_in[19];
  const float* lin2_w   = (const float*)d_in[20];
  const float* lin2_b   = (const float*)d_in[21];

  int N = in_sizes[0];
  int E = in_sizes[1] / 2;
  int G = out_size / 3;
  const int* esrc = edge;
  const int* edst = edge + E;
  int NB = (N + (1 << BBITS) - 1) >> BBITS;
  if (NB > 128) NB = 128;

  size_t off = 0;
  auto alloc = [&](size_t bytes) -> char* {
    char* p = (char*)d_ws + off;
    off += (bytes + 255) & ~(size_t)255;
    return p;
  };
  int SB = (N + 255) / 256;
  int*    deg    = (int*)alloc((size_t)N * 4);
  int*    rp     = (int*)alloc((size_t)(N + 1) * 4);
  int*    col    = (int*)alloc((size_t)E * 4);
  int*    bsum   = (int*)alloc((size_t)SB * 4);
  int*    boff   = (int*)alloc((size_t)SB * 4);
  int*    bc     = (int*)alloc((size_t)128 * 16 * 4);
  uint*   arena  = (uint*)alloc((size_t)NB * BCAP * 4);
  int*    gs     = (int*)alloc((size_t)(G + 1) * 4);
  ushort* wpack  = (ushort*)alloc((size_t)16 * 8192 * 2);
  float*  z0buf  = (float*)alloc((size_t)N * 4);
  ushort* hA     = (ushort*)alloc((size_t)N * 64 * 2);
  ushort* hB     = (ushort*)alloc((size_t)N * 64 * 2);
  float*  pooled = (float*)alloc((size_t)G * 512 * 4);
  (void)ws_size;

  // atomic-free binned CSC build (packed arena)
  init_bc_kernel<<<1, 128, 0, stream>>>(bc, NB);
  int ebA = (E + 4095) / 4096;
  bin_edges_kernel<<<ebA, 1024, 0, stream>>>(esrc, edst, bc, arena, E);
  bucket_count_kernel<<<NB, 1024, 0, stream>>>(arena, bc, deg, N);
  scan_blocksums<<<SB, 256, 0, stream>>>(deg, bsum, N);
  scan_bsum<<<1, 1024, 0, stream>>>(bsum, boff, rp + N, SB);
  scan_final<<<SB, 256, 0, stream>>>(deg, boff, rp, N);
  bucket_scatter_kernel<<<NB, 1024, 0, stream>>>(arena, bc, rp, col, N);

  graph_bounds_kernel<<<SB, 256, 0, stream>>>(batch, gs, N, G);
  prepack_w_kernel<<<16, 256, 0, stream>>>(W1_rest, W2, wpack);
  (void)hipMemsetAsync(pooled, 0, (size_t)G * 512 * 4, stream);

  int nb = (N + 127) / 128;
  z0_kernel<<<SB, 256, 0, stream>>>(x, rp, col, eps, z0buf, N);
  fused_layer_kernel<<<nb, 512, 0, stream>>>(hA, z0buf, W1_first, hA,
      rp, col, eps, wpack, wpack + 8192,
      b1, g1, be1, m1, v1, b2, g2, be2, m2, v2, batch, pooled, 0, 1, N);

  ushort* hin = hA;
  ushort* hout = hB;
  for (int i = 1; i < 8; ++i) {
    fused_layer_kernel<<<nb, 512, 0, stream>>>(hin, z0buf, W1_first, hout,
        rp, col, eps,
        wpack + (size_t)(2 * i) * 8192, wpack + (size_t)(2 * i + 1) * 8192,
        b1 + i * 64, g1 + i * 64, be1 + i * 64, m1 + i * 64, v1 + i * 64,
        b2 + i * 64, g2 + i * 64, be2 + i * 64, m2 + i * 64, v2 + i * 64,
        batch, pooled, i, 0, N);
    ushort* t = hin; hin = hout; hout = t;
  }
  final_kernel<<<G, 64, 0, stream>>>(pooled, gs, lin1_w, lin1_b,
                                     lin2_w, lin2_b, (float*)d_out, G);
}

// Round 6
// 569.797 us; speedup vs baseline: 8.7680x; 8.7680x over previous
//
#include <hip/hip_runtime.h>
#include <hip/hip_bf16.h>
#include <math.h>

// ---------------------------------------------------------------------------
// GIN + JumpingKnowledge(cat) + mean-pool + 2-layer head, eval mode.
// R22 (on R19, 518us; R20 56us/layer and R21 LDS-atomic 692us/layer both
// REVERTED): R19 structure + quad-PAIR interleaved agg.
//  - agg processes quads (0,1) then (2,3); each pair keeps two cursors +
//    two accumulator sets and issues 4+4 gathers per lane per granule.
//    Dependent vmcnt-drain chains per wave: ~8 -> ~4-5 (pair executes
//    max(gA,gB) granules, not gA+gB). ~10% masked-load waste.
//  - dummy loads for exhausted quads clamp to col[0] (valid), mask 0.
// Keeps: R19 fusion (z in sbuf f32 -> MFMA MLP -> pool), 512thr/128 nodes,
// plain col=src packing, R15/R16 build/z0/split-bf16 MFMA/pool/final.
// ---------------------------------------------------------------------------

typedef unsigned int uint;
typedef unsigned short ushort;
typedef __attribute__((ext_vector_type(8))) short short8;
typedef __attribute__((ext_vector_type(4))) float floatx4;
typedef __attribute__((ext_vector_type(4))) uint uintx4;

#define BBITS 10                 // 1024 nodes per bucket
#define BCAP 20480               // arena capacity per bucket
#define BMASK ((1 << BBITS) - 1)

__device__ __forceinline__ float bf_lo(uint w) { return __uint_as_float(w << 16); }
__device__ __forceinline__ float bf_hi(uint w) { return __uint_as_float(w & 0xffff0000u); }

__device__ __forceinline__ ushort f2bf(float x) {
  __hip_bfloat16 h = __float2bfloat16(x);
  return *(ushort*)&h;
}
__device__ __forceinline__ float bf2f(ushort u) { return __uint_as_float((uint)u << 16); }

__device__ __forceinline__ uint pack_bf16(float a, float b) {
  return (uint)f2bf(a) | ((uint)f2bf(b) << 16);
}

// combine the two edge-slots (lane ^ 8) of a 16-lane node-row: one level.
__device__ __forceinline__ float slot_combine(float v) {
  return v + __shfl_xor(v, 8, 64);
}

__device__ __forceinline__ void split8(float4 u0, float4 u1, short8& hi, short8& lo) {
  float v0 = u0.x, v1 = u0.y, v2 = u0.z, v3 = u0.w;
  float v4 = u1.x, v5 = u1.y, v6 = u1.z, v7 = u1.w;
  ushort h0 = f2bf(v0), h1 = f2bf(v1), h2 = f2bf(v2), h3 = f2bf(v3);
  ushort h4 = f2bf(v4), h5 = f2bf(v5), h6 = f2bf(v6), h7 = f2bf(v7);
  hi[0] = (short)h0; hi[1] = (short)h1; hi[2] = (short)h2; hi[3] = (short)h3;
  hi[4] = (short)h4; hi[5] = (short)h5; hi[6] = (short)h6; hi[7] = (short)h7;
  lo[0] = (short)f2bf(v0 - bf2f(h0)); lo[1] = (short)f2bf(v1 - bf2f(h1));
  lo[2] = (short)f2bf(v2 - bf2f(h2)); lo[3] = (short)f2bf(v3 - bf2f(h3));
  lo[4] = (short)f2bf(v4 - bf2f(h4)); lo[5] = (short)f2bf(v5 - bf2f(h5));
  lo[6] = (short)f2bf(v6 - bf2f(h6)); lo[7] = (short)f2bf(v7 - bf2f(h7));
}

__device__ __forceinline__ short8 hi8(float4 u0, float4 u1) {
  short8 h;
  h[0] = (short)f2bf(u0.x); h[1] = (short)f2bf(u0.y);
  h[2] = (short)f2bf(u0.z); h[3] = (short)f2bf(u0.w);
  h[4] = (short)f2bf(u1.x); h[5] = (short)f2bf(u1.y);
  h[6] = (short)f2bf(u1.z); h[7] = (short)f2bf(u1.w);
  return h;
}

// ---- atomic-free binned CSC build (packed arena) ---------------------------

__global__ void init_bc_kernel(int* __restrict__ bc, int NB) {
  int b = threadIdx.x;
  if (b < NB) bc[b * 16] = b * BCAP;
}

__global__ __launch_bounds__(1024) void bin_edges_kernel(
    const int* __restrict__ src, const int* __restrict__ dst, int* __restrict__ bc,
    uint* __restrict__ arena, int E) {
  __shared__ int cnt[128], base[128];
  for (long chunk = (long)blockIdx.x * 4096; chunk < E; chunk += (long)gridDim.x * 4096) {
    if (threadIdx.x < 128) cnt[threadIdx.x] = 0;
    __syncthreads();
    uint v[4];
    int b[4], r[4];
#pragma unroll
    for (int u = 0; u < 4; ++u) {
      long e = chunk + threadIdx.x + u * 1024;
      if (e < E) {
        int s = src[e];
        int d = dst[e];
        b[u] = d >> BBITS;
        v[u] = ((uint)s << BBITS) | (uint)(d & BMASK);
        r[u] = atomicAdd(&cnt[b[u]], 1);
      }
    }
    __syncthreads();
    if (threadIdx.x < 128)
      base[threadIdx.x] = cnt[threadIdx.x] ? atomicAdd(&bc[threadIdx.x * 16], cnt[threadIdx.x]) : 0;
    __syncthreads();
#pragma unroll
    for (int u = 0; u < 4; ++u) {
      long e = chunk + threadIdx.x + u * 1024;
      if (e < E) arena[base[b[u]] + r[u]] = v[u];
    }
    __syncthreads();
  }
}

__global__ __launch_bounds__(1024) void bucket_count_kernel(
    const uint* __restrict__ arena, const int* __restrict__ bc,
    int* __restrict__ deg, int N) {
  __shared__ int hist[1 << BBITS];
  int b = blockIdx.x;
  int lo = b << BBITS;
  int hi = min(lo + (1 << BBITS), N);
  hist[threadIdx.x] = 0;
  __syncthreads();
  int cnt = bc[b * 16] - b * BCAP;
  const uint* ad = arena + (size_t)b * BCAP;
  for (int i = threadIdx.x; i < cnt; i += 1024) atomicAdd(&hist[ad[i] & BMASK], 1);
  __syncthreads();
  if (lo + (int)threadIdx.x < hi) deg[lo + threadIdx.x] = hist[threadIdx.x];
}

__global__ __launch_bounds__(1024) void bucket_scatter_kernel(
    const uint* __restrict__ arena, const int* __restrict__ bc,
    const int* __restrict__ rp, int* __restrict__ col, int N) {
  __shared__ int cur[1 << BBITS];
  int b = blockIdx.x;
  int lo = b << BBITS;
  int hi = min(lo + (1 << BBITS), N);
  if (lo + (int)threadIdx.x < hi) cur[threadIdx.x] = rp[lo + threadIdx.x];
  __syncthreads();
  int cnt = bc[b * 16] - b * BCAP;
  const uint* ad = arena + (size_t)b * BCAP;
  for (int i = threadIdx.x; i < cnt; i += 1024) {
    uint v = ad[i];
    int pos = atomicAdd(&cur[v & BMASK], 1);
    col[pos] = (int)(v >> BBITS);
  }
}

// ---- scan -----------------------------------------------------------------
__global__ void scan_blocksums(const int* __restrict__ deg, int* __restrict__ bsum, int N) {
  __shared__ int red[256];
  int i = blockIdx.x * 256 + threadIdx.x;
  red[threadIdx.x] = (i < N) ? deg[i] : 0;
  __syncthreads();
  for (int off = 128; off > 0; off >>= 1) {
    if (threadIdx.x < off) red[threadIdx.x] += red[threadIdx.x + off];
    __syncthreads();
  }
  if (threadIdx.x == 0) bsum[blockIdx.x] = red[0];
}

__global__ void scan_bsum(const int* __restrict__ bsum, int* __restrict__ boff,
                          int* __restrict__ rp_last, int B) {
  __shared__ int tmp[1024];
  int t = threadIdx.x;
  int v = (t < B) ? bsum[t] : 0;
  tmp[t] = v;
  __syncthreads();
  for (int off = 1; off < 1024; off <<= 1) {
    int u = (t >= off) ? tmp[t - off] : 0;
    __syncthreads();
    tmp[t] += u;
    __syncthreads();
  }
  if (t < B) boff[t] = tmp[t] - v;
  if (t == 1023) *rp_last = tmp[1023];
}

__global__ void scan_final(const int* __restrict__ deg, const int* __restrict__ boff,
                           int* __restrict__ rp, int N) {
  __shared__ int tmp[256];
  int i = blockIdx.x * 256 + threadIdx.x;
  int v = (i < N) ? deg[i] : 0;
  tmp[threadIdx.x] = v;
  __syncthreads();
  for (int off = 1; off < 256; off <<= 1) {
    int u = (threadIdx.x >= off) ? tmp[threadIdx.x - off] : 0;
    __syncthreads();
    tmp[threadIdx.x] += u;
    __syncthreads();
  }
  if (i < N) rp[i] = boff[blockIdx.x] + tmp[threadIdx.x] - v;
}

__global__ void graph_bounds_kernel(const int* __restrict__ batch, int* __restrict__ gs,
                                    int N, int G) {
  int n = blockIdx.x * 256 + threadIdx.x;
  if (n >= N) return;
  int b = batch[n];
  int bp = (n == 0) ? -1 : batch[n - 1];
  for (int g = bp + 1; g <= b; ++g) gs[g] = n;
  if (n == N - 1)
    for (int g = b + 1; g <= G; ++g) gs[g] = N;
}

// Prepack W1/W2 into MFMA B-fragment order, split hi/lo bf16.
__global__ void prepack_w_kernel(const float* __restrict__ W1_rest,
                                 const float* __restrict__ W2, ushort* __restrict__ wp) {
  int l = blockIdx.x >> 1, g = blockIdx.x & 1;
  const float* W;
  if (g == 0) {
    if (l == 0) return;
    W = W1_rest + (size_t)(l - 1) * 4096;
  } else {
    W = W2 + (size_t)l * 4096;
  }
  ushort* out = wp + (size_t)(l * 2 + g) * 8192;
  for (int idx = threadIdx.x; idx < 4096; idx += blockDim.x) {
    int j = idx & 7, lane = (idx >> 3) & 63, ks = (idx >> 9) & 1, nt = (idx >> 10) & 3;
    int k = ks * 32 + (lane >> 4) * 8 + j;
    int n = nt * 16 + (lane & 15);
    float w = W[k * 64 + n];
    ushort hi = f2bf(w);
    ushort lo = f2bf(w - bf2f(hi));
    size_t base = (size_t)((nt * 2 + ks) * 2) * 512 + lane * 8 + j;
    out[base] = hi;
    out[base + 512] = lo;
  }
}

// ---------------------------------------------------------------------------
// Fused GIN layer: agg prologue (quad-pair interleaved, z into sbuf f32) +
// MFMA MLP + mean-pool. 128 nodes/block, 512 threads.
// ---------------------------------------------------------------------------
__global__ __launch_bounds__(512) void fused_layer_kernel(
    const ushort* __restrict__ hb, const float* __restrict__ z0,
    const float* __restrict__ W1f, ushort* __restrict__ hout,
    const int* __restrict__ rp, const int* __restrict__ col,
    const float* __restrict__ eps,
    const ushort* __restrict__ wp1, const ushort* __restrict__ wp2,
    const float* __restrict__ b1, const float* __restrict__ g1,
    const float* __restrict__ be1, const float* __restrict__ m1,
    const float* __restrict__ v1,
    const float* __restrict__ b2, const float* __restrict__ g2,
    const float* __restrict__ be2, const float* __restrict__ m2,
    const float* __restrict__ v2,
    const int* __restrict__ batch, float* __restrict__ pooled,
    int layer, int skip1, int N) {
  __shared__ float bnp[6][64];
  __shared__ float w1fl[64];
  __shared__ float sbuf[128][68];  // phase0: z rows; phase1: t rows; epilogue: h
  __shared__ int batchl[128];
  int tid = threadIdx.x;
  int blockbase = blockIdx.x * 128;
  if (tid < 64) {
    bnp[0][tid] = b1[tid];
    float s1 = g1[tid] * rsqrtf(v1[tid] + 1e-5f);
    bnp[1][tid] = s1;
    bnp[2][tid] = be1[tid] - m1[tid] * s1;
    bnp[3][tid] = b2[tid];
    float s2 = g2[tid] * rsqrtf(v2[tid] + 1e-5f);
    bnp[4][tid] = s2;
    bnp[5][tid] = be2[tid] - m2[tid] * s2;
    if (skip1) w1fl[tid] = W1f[tid];
  }
  if (tid < 128) batchl[tid] = (blockbase + tid < N) ? batch[blockbase + tid] : -1;
  __syncthreads();
  int wave = tid >> 6, lane = tid & 63;
  int q = lane >> 4, c = lane & 15;
  int base = blockbase + wave * 16;
  int srow = wave * 16;  // this wave's strip base row in sbuf

  short8 ahi0, alo0, ahi1, alo1;
  if (!skip1) {
    // ---- agg prologue: wave's 16 nodes as 2 interleaved quad-PAIRS.
    // Each pair runs two 4-deep gather streams (8 loads in flight/lane).
    int ni = lane >> 4;          // node within quad (== q)
    int s = (lane >> 3) & 1;     // edge slot
    int r = lane & 7;            // 16B chunk
    float ep = 1.0f + eps[layer];
    for (int qp = 0; qp < 2; ++qp) {
      int nodeA = base + qp * 8 + ni;
      int nodeB = nodeA + 4;
      bool vA = nodeA < N, vB = nodeB < N;
      int nA = vA ? nodeA : (N - 1);
      int nB = vB ? nodeB : (N - 1);
      int begA = rp[nA];
      int endA = vA ? rp[nA + 1] : begA;
      int begB = rp[nB];
      int endB = vB ? rp[nB + 1] : begB;
      float a[8] = {0.f, 0.f, 0.f, 0.f, 0.f, 0.f, 0.f, 0.f};
      float b[8] = {0.f, 0.f, 0.f, 0.f, 0.f, 0.f, 0.f, 0.f};
      int eA = begA + s, eB = begB + s;
      while (eA < endA || eB < endB) {
        int cA[4], cB[4];
        float mA[4], mB[4];
#pragma unroll
        for (int k = 0; k < 4; ++k) {
          int ec = eA + 2 * k;
          bool ok = ec < endA;
          mA[k] = ok ? 1.0f : 0.0f;
          cA[k] = __builtin_nontemporal_load(col + (ok ? ec : 0));
          ec = eB + 2 * k;
          ok = ec < endB;
          mB[k] = ok ? 1.0f : 0.0f;
          cB[k] = __builtin_nontemporal_load(col + (ok ? ec : 0));
        }
        uint4 wA[4], wB[4];
#pragma unroll
        for (int k = 0; k < 4; ++k) {
          wA[k] = ((const uint4*)(hb + (long)cA[k] * 64))[r];
          wB[k] = ((const uint4*)(hb + (long)cB[k] * 64))[r];
        }
#pragma unroll
        for (int k = 0; k < 4; ++k) {
          a[0] = fmaf(mA[k], bf_lo(wA[k].x), a[0]);
          a[1] = fmaf(mA[k], bf_hi(wA[k].x), a[1]);
          a[2] = fmaf(mA[k], bf_lo(wA[k].y), a[2]);
          a[3] = fmaf(mA[k], bf_hi(wA[k].y), a[3]);
          a[4] = fmaf(mA[k], bf_lo(wA[k].z), a[4]);
          a[5] = fmaf(mA[k], bf_hi(wA[k].z), a[5]);
          a[6] = fmaf(mA[k], bf_lo(wA[k].w), a[6]);
          a[7] = fmaf(mA[k], bf_hi(wA[k].w), a[7]);
          b[0] = fmaf(mB[k], bf_lo(wB[k].x), b[0]);
          b[1] = fmaf(mB[k], bf_hi(wB[k].x), b[1]);
          b[2] = fmaf(mB[k], bf_lo(wB[k].y), b[2]);
          b[3] = fmaf(mB[k], bf_hi(wB[k].y), b[3]);
          b[4] = fmaf(mB[k], bf_lo(wB[k].z), b[4]);
          b[5] = fmaf(mB[k], bf_hi(wB[k].z), b[5]);
          b[6] = fmaf(mB[k], bf_lo(wB[k].w), b[6]);
          b[7] = fmaf(mB[k], bf_hi(wB[k].w), b[7]);
        }
        eA += 8;
        eB += 8;
      }
#pragma unroll
      for (int j = 0; j < 8; ++j) {
        a[j] = slot_combine(a[j]);
        b[j] = slot_combine(b[j]);
      }
      if (s == 0) {
        uint4 hv = ((const uint4*)(hb + (long)nA * 64))[r];
        float v0 = fmaf(ep, bf_lo(hv.x), a[0]), v1 = fmaf(ep, bf_hi(hv.x), a[1]);
        float v2 = fmaf(ep, bf_lo(hv.y), a[2]), v3 = fmaf(ep, bf_hi(hv.y), a[3]);
        float v4 = fmaf(ep, bf_lo(hv.z), a[4]), v5 = fmaf(ep, bf_hi(hv.z), a[5]);
        float v6 = fmaf(ep, bf_lo(hv.w), a[6]), v7 = fmaf(ep, bf_hi(hv.w), a[7]);
        int rowA = srow + qp * 8 + ni;
        *(float4*)&sbuf[rowA][r * 8] = make_float4(v0, v1, v2, v3);
        *(float4*)&sbuf[rowA][r * 8 + 4] = make_float4(v4, v5, v6, v7);
        hv = ((const uint4*)(hb + (long)nB * 64))[r];
        v0 = fmaf(ep, bf_lo(hv.x), b[0]); v1 = fmaf(ep, bf_hi(hv.x), b[1]);
        v2 = fmaf(ep, bf_lo(hv.y), b[2]); v3 = fmaf(ep, bf_hi(hv.y), b[3]);
        v4 = fmaf(ep, bf_lo(hv.z), b[4]); v5 = fmaf(ep, bf_hi(hv.z), b[5]);
        v6 = fmaf(ep, bf_lo(hv.w), b[6]); v7 = fmaf(ep, bf_hi(hv.w), b[7]);
        *(float4*)&sbuf[rowA + 4][r * 8] = make_float4(v0, v1, v2, v3);
        *(float4*)&sbuf[rowA + 4][r * 8 + 4] = make_float4(v4, v5, v6, v7);
      }
    }
    // ---- A-fragments from sbuf z rows (same-wave in-order LDS)
    {
      float4 u0 = *(const float4*)&sbuf[srow + c][q * 8];
      float4 u1 = *(const float4*)&sbuf[srow + c][q * 8 + 4];
      ahi0 = hi8(u0, u1);
      u0 = *(const float4*)&sbuf[srow + c][32 + q * 8];
      u1 = *(const float4*)&sbuf[srow + c][32 + q * 8 + 4];
      ahi1 = hi8(u0, u1);
    }
    floatx4 acc[4];
#pragma unroll
    for (int nt = 0; nt < 4; ++nt) acc[nt] = (floatx4){0.f, 0.f, 0.f, 0.f};
#pragma unroll
    for (int nt = 0; nt < 4; ++nt) {
#pragma unroll
      for (int ks = 0; ks < 2; ++ks) {
        const ushort* fb = wp1 + ((nt * 2 + ks) * 2) * 512 + lane * 8;
        short8 bh = *(const short8*)fb;
        short8 bl = *(const short8*)(fb + 512);
        short8 ah = ks ? ahi1 : ahi0;
        acc[nt] = __builtin_amdgcn_mfma_f32_16x16x32_bf16(ah, bh, acc[nt], 0, 0, 0);
        acc[nt] = __builtin_amdgcn_mfma_f32_16x16x32_bf16(ah, bl, acc[nt], 0, 0, 0);
      }
    }
#pragma unroll
    for (int nt = 0; nt < 4; ++nt) {
      int feat = nt * 16 + c;
      float s1 = bnp[1][feat], o1 = bnp[2][feat], bb = bnp[0][feat];
#pragma unroll
      for (int r2 = 0; r2 < 4; ++r2) {
        float y = fmaxf(acc[nt][r2] + bb, 0.f);
        sbuf[srow + q * 4 + r2][feat] = fmaf(y, s1, o1);
      }
    }
    float4 u0 = *(const float4*)&sbuf[srow + c][q * 8];
    float4 u1 = *(const float4*)&sbuf[srow + c][q * 8 + 4];
    split8(u0, u1, ahi0, alo0);
    u0 = *(const float4*)&sbuf[srow + c][32 + q * 8];
    u1 = *(const float4*)&sbuf[srow + c][32 + q * 8 + 4];
    split8(u0, u1, ahi1, alo1);
  } else {
    long row = base + c;
    if (row >= N) row = N - 1;
    float zv = z0[row];
    float4 t00, t01, t10, t11;
    {
      float tv[8];
#pragma unroll
      for (int j = 0; j < 8; ++j) {
        int k = q * 8 + j;
        float y = fmaxf(fmaf(zv, w1fl[k], bnp[0][k]), 0.f);
        tv[j] = fmaf(y, bnp[1][k], bnp[2][k]);
      }
      t00 = make_float4(tv[0], tv[1], tv[2], tv[3]);
      t01 = make_float4(tv[4], tv[5], tv[6], tv[7]);
#pragma unroll
      for (int j = 0; j < 8; ++j) {
        int k = 32 + q * 8 + j;
        float y = fmaxf(fmaf(zv, w1fl[k], bnp[0][k]), 0.f);
        tv[j] = fmaf(y, bnp[1][k], bnp[2][k]);
      }
      t10 = make_float4(tv[0], tv[1], tv[2], tv[3]);
      t11 = make_float4(tv[4], tv[5], tv[6], tv[7]);
    }
    split8(t00, t01, ahi0, alo0);
    split8(t10, t11, ahi1, alo1);
  }

  // GEMM2: 3-term
  floatx4 acc2[4];
#pragma unroll
  for (int nt = 0; nt < 4; ++nt) acc2[nt] = (floatx4){0.f, 0.f, 0.f, 0.f};
#pragma unroll
  for (int nt = 0; nt < 4; ++nt) {
#pragma unroll
    for (int ks = 0; ks < 2; ++ks) {
      const ushort* fb = wp2 + ((nt * 2 + ks) * 2) * 512 + lane * 8;
      short8 bh = *(const short8*)fb;
      short8 bl = *(const short8*)(fb + 512);
      short8 ah = ks ? ahi1 : ahi0;
      short8 al = ks ? alo1 : alo0;
      acc2[nt] = __builtin_amdgcn_mfma_f32_16x16x32_bf16(ah, bh, acc2[nt], 0, 0, 0);
      acc2[nt] = __builtin_amdgcn_mfma_f32_16x16x32_bf16(al, bh, acc2[nt], 0, 0, 0);
      acc2[nt] = __builtin_amdgcn_mfma_f32_16x16x32_bf16(ah, bl, acc2[nt], 0, 0, 0);
    }
  }

  // bn2 -> stage vals in sbuf (wave-local rows)
#pragma unroll
  for (int nt = 0; nt < 4; ++nt) {
    int feat = nt * 16 + c;
    float s2 = bnp[4][feat], o2 = bnp[5][feat], bb = bnp[3][feat];
#pragma unroll
    for (int r2 = 0; r2 < 4; ++r2) {
      int node = base + q * 4 + r2;
      float val = 0.f;
      if (node < N) {
        float y = fmaxf(acc2[nt][r2] + bb, 0.f);
        val = fmaf(y, s2, o2);
      }
      sbuf[srow + q * 4 + r2][feat] = val;
    }
  }
  __syncthreads();

  // vectorized h stores: 128 rows x 8 chunks of 16B; 2 chunks/thread
#pragma unroll
  for (int it = 0; it < 2; ++it) {
    int chunk = tid + it * 512;
    int row = chunk >> 3, c8 = chunk & 7;
    int node = blockbase + row;
    if (node < N) {
      const float* sp = &sbuf[row][c8 * 8];
      uintx4 w;
      w.x = pack_bf16(sp[0], sp[1]);
      w.y = pack_bf16(sp[2], sp[3]);
      w.z = pack_bf16(sp[4], sp[5]);
      w.w = pack_bf16(sp[6], sp[7]);
      *(uintx4*)(hout + (long)node * 64 + c8 * 8) = w;
    }
  }

  // parallel segment sums: 256 threads = feat(64) x quarter(4), 32 rows each
  if (tid < 256) {
    int j = tid & 63;
    int quarter = tid >> 6;
    int nvalid = N - blockbase;
    if (nvalid > 128) nvalid = 128;
    int i = quarter * 32;
    int iend = i + 32;
    if (iend > nvalid) iend = nvalid;
    while (i < iend) {
      int g = batchl[i];
      float s = 0.f;
      while (i < iend && batchl[i] == g) { s += sbuf[i][j]; ++i; }
      atomicAdd(&pooled[(size_t)g * 512 + layer * 64 + j], s);
    }
  }
}

__global__ void z0_kernel(const float* __restrict__ x, const int* __restrict__ rp,
                          const int* __restrict__ col, const float* __restrict__ eps,
                          float* __restrict__ z0, int N) {
  int n = blockIdx.x * blockDim.x + threadIdx.x;
  if (n >= N) return;
  int beg = rp[n], end = rp[n + 1];
  float a = 0.f;
  for (int e = beg; e < end; ++e) a += x[col[e]];
  z0[n] = fmaf(1.0f + eps[0], x[n], a);
}

__global__ __launch_bounds__(64) void final_kernel(
    const float* __restrict__ pooled, const int* __restrict__ gs,
    const float* __restrict__ lin1_w, const float* __restrict__ lin1_b,
    const float* __restrict__ lin2_w, const float* __restrict__ lin2_b,
    float* __restrict__ out, int G) {
  int g = blockIdx.x;
  int j = threadIdx.x;
  float inv = 1.0f / fmaxf((float)(gs[g + 1] - gs[g]), 1.0f);
  __shared__ float p[512];
  for (int t = j; t < 512; t += 64) p[t] = pooled[(long)g * 512 + t] * inv;
  __syncthreads();
  float a0 = lin1_b[j], a1 = 0.f, a2 = 0.f, a3 = 0.f;
  for (int k = 0; k < 512; k += 4) {
    a0 = fmaf(p[k + 0], lin1_w[(k + 0) * 64 + j], a0);
    a1 = fmaf(p[k + 1], lin1_w[(k + 1) * 64 + j], a1);
    a2 = fmaf(p[k + 2], lin1_w[(k + 2) * 64 + j], a2);
    a3 = fmaf(p[k + 3], lin1_w[(k + 3) * 64 + j], a3);
  }
  float hv = fmaxf((a0 + a1) + (a2 + a3), 0.f);
  __shared__ float hb[64];
  hb[j] = hv;
  __syncthreads();
  __shared__ float lg[3];
  if (j < 3) {
    float a = lin2_b[j];
#pragma unroll
    for (int k = 0; k < 64; ++k) a = fmaf(hb[k], lin2_w[k * 3 + j], a);
    lg[j] = a;
  }
  __syncthreads();
  if (j < 3) {
    float mx = fmaxf(fmaxf(lg[0], lg[1]), lg[2]);
    float lse = mx + logf(expf(lg[0] - mx) + expf(lg[1] - mx) + expf(lg[2] - mx));
    out[g * 3 + j] = lg[j] - lse;
  }
}

extern "C" void kernel_launch(void* const* d_in, const int* in_sizes, int n_in,
                              void* d_out, int out_size, void* d_ws, size_t ws_size,
                              hipStream_t stream) {
  const float* x        = (const float*)d_in[0];
  const int*   edge     = (const int*)d_in[1];
  const int*   batch    = (const int*)d_in[2];
  const float* eps      = (const float*)d_in[4];
  const float* W1_first = (const float*)d_in[5];
  const float* W1_rest  = (const float*)d_in[6];
  const float* b1       = (const float*)d_in[7];
  const float* g1       = (const float*)d_in[8];
  const float* be1      = (const float*)d_in[9];
  const float* m1       = (const float*)d_in[10];
  const float* v1       = (const float*)d_in[11];
  const float* W2       = (const float*)d_in[12];
  const float* b2       = (const float*)d_in[13];
  const float* g2       = (const float*)d_in[14];
  const float* be2      = (const float*)d_in[15];
  const float* m2       = (const float*)d_in[16];
  const float* v2       = (const float*)d_in[17];
  const float* lin1_w   = (const float*)d_in[18];
  const float* lin1_b   = (const float*)d_in[19];
  const float* lin2_w   = (const float*)d_in[20];
  const float* lin2_b   = (const float*)d_in[21];

  int N = in_sizes[0];
  int E = in_sizes[1] / 2;
  int G = out_size / 3;
  const int* esrc = edge;
  const int* edst = edge + E;
  int NB = (N + (1 << BBITS) - 1) >> BBITS;
  if (NB > 128) NB = 128;

  size_t off = 0;
  auto alloc = [&](size_t bytes) -> char* {
    char* p = (char*)d_ws + off;
    off += (bytes + 255) & ~(size_t)255;
    return p;
  };
  int SB = (N + 255) / 256;
  int*    deg    = (int*)alloc((size_t)N * 4);
  int*    rp     = (int*)alloc((size_t)(N + 1) * 4);
  int*    col    = (int*)alloc((size_t)E * 4);
  int*    bsum   = (int*)alloc((size_t)SB * 4);
  int*    boff   = (int*)alloc((size_t)SB * 4);
  int*    bc     = (int*)alloc((size_t)128 * 16 * 4);
  uint*   arena  = (uint*)alloc((size_t)NB * BCAP * 4);
  int*    gs     = (int*)alloc((size_t)(G + 1) * 4);
  ushort* wpack  = (ushort*)alloc((size_t)16 * 8192 * 2);
  float*  z0buf  = (float*)alloc((size_t)N * 4);
  ushort* hA     = (ushort*)alloc((size_t)N * 64 * 2);
  ushort* hB     = (ushort*)alloc((size_t)N * 64 * 2);
  float*  pooled = (float*)alloc((size_t)G * 512 * 4);
  (void)ws_size;

  // atomic-free binned CSC build (packed arena)
  init_bc_kernel<<<1, 128, 0, stream>>>(bc, NB);
  int ebA = (E + 4095) / 4096;
  bin_edges_kernel<<<ebA, 1024, 0, stream>>>(esrc, edst, bc, arena, E);
  bucket_count_kernel<<<NB, 1024, 0, stream>>>(arena, bc, deg, N);
  scan_blocksums<<<SB, 256, 0, stream>>>(deg, bsum, N);
  scan_bsum<<<1, 1024, 0, stream>>>(bsum, boff, rp + N, SB);
  scan_final<<<SB, 256, 0, stream>>>(deg, boff, rp, N);
  bucket_scatter_kernel<<<NB, 1024, 0, stream>>>(arena, bc, rp, col, N);

  graph_bounds_kernel<<<SB, 256, 0, stream>>>(batch, gs, N, G);
  prepack_w_kernel<<<16, 256, 0, stream>>>(W1_rest, W2, wpack);
  (void)hipMemsetAsync(pooled, 0, (size_t)G * 512 * 4, stream);

  int nb = (N + 127) / 128;
  z0_kernel<<<SB, 256, 0, stream>>>(x, rp, col, eps, z0buf, N);
  fused_layer_kernel<<<nb, 512, 0, stream>>>(hA, z0buf, W1_first, hA,
      rp, col, eps, wpack, wpack + 8192,
      b1, g1, be1, m1, v1, b2, g2, be2, m2, v2, batch, pooled, 0, 1, N);

  ushort* hin = hA;
  ushort* hout = hB;
  for (int i = 1; i < 8; ++i) {
    fused_layer_kernel<<<nb, 512, 0, stream>>>(hin, z0buf, W1_first, hout,
        rp, col, eps,
        wpack + (size_t)(2 * i) * 8192, wpack + (size_t)(2 * i + 1) * 8192,
        b1 + i * 64, g1 + i * 64, be1 + i * 64, m1 + i * 64, v1 + i * 64,
        b2 + i * 64, g2 + i * 64, be2 + i * 64, m2 + i * 64, v2 + i * 64,
        batch, pooled, i, 0, N);
    ushort* t = hin; hin = hout; hout = t;
  }
  final_kernel<<<G, 64, 0, stream>>>(pooled, gs, lin1_w, lin1_b,
                                     lin2_w, lin2_b, (float*)d_out, G);
}

// Round 7
// 558.796 us; speedup vs baseline: 8.9406x; 1.0197x over previous
//
#include <hip/hip_runtime.h>
#include <hip/hip_bf16.h>
#include <math.h>

// ---------------------------------------------------------------------------
// GIN + JumpingKnowledge(cat) + mean-pool + 2-layer head, eval mode.
// R23 (on R19, 518us; R20/R21/R22 all regressed and are reverted):
// R19 structure + two latency-overlap transforms in the agg quad loop:
//  - software-pipelined col loads: granule g+1's col indices issue right
//    after granule g's gathers -> col latency hides under gather wait
//    (counted vmcnt keeps them outstanding). Chain/granule ~1000 -> ~600cy.
//  - hv self-term load hoisted above the while loop (all lanes issue, s==0
//    consumes; same rows, no extra lines) -> removes ~600cy/quad stall.
//  - VGPR +~10 only (R20/R22 showed VGPR>=52 variants regress occupancy).
// Keeps: R19 fusion (z in sbuf f32 -> MFMA MLP -> pool), 512thr/128 nodes,
// R15/R16 build/z0/split-bf16 MFMA/pool/final.
// ---------------------------------------------------------------------------

typedef unsigned int uint;
typedef unsigned short ushort;
typedef __attribute__((ext_vector_type(8))) short short8;
typedef __attribute__((ext_vector_type(4))) float floatx4;
typedef __attribute__((ext_vector_type(4))) uint uintx4;

#define BBITS 10                 // 1024 nodes per bucket
#define BCAP 20480               // arena capacity per bucket
#define BMASK ((1 << BBITS) - 1)

__device__ __forceinline__ float bf_lo(uint w) { return __uint_as_float(w << 16); }
__device__ __forceinline__ float bf_hi(uint w) { return __uint_as_float(w & 0xffff0000u); }

__device__ __forceinline__ ushort f2bf(float x) {
  __hip_bfloat16 h = __float2bfloat16(x);
  return *(ushort*)&h;
}
__device__ __forceinline__ float bf2f(ushort u) { return __uint_as_float((uint)u << 16); }

__device__ __forceinline__ uint pack_bf16(float a, float b) {
  return (uint)f2bf(a) | ((uint)f2bf(b) << 16);
}

// combine the two edge-slots (lane ^ 8) of a 16-lane node-row: one level.
__device__ __forceinline__ float slot_combine(float v) {
  return v + __shfl_xor(v, 8, 64);
}

__device__ __forceinline__ void split8(float4 u0, float4 u1, short8& hi, short8& lo) {
  float v0 = u0.x, v1 = u0.y, v2 = u0.z, v3 = u0.w;
  float v4 = u1.x, v5 = u1.y, v6 = u1.z, v7 = u1.w;
  ushort h0 = f2bf(v0), h1 = f2bf(v1), h2 = f2bf(v2), h3 = f2bf(v3);
  ushort h4 = f2bf(v4), h5 = f2bf(v5), h6 = f2bf(v6), h7 = f2bf(v7);
  hi[0] = (short)h0; hi[1] = (short)h1; hi[2] = (short)h2; hi[3] = (short)h3;
  hi[4] = (short)h4; hi[5] = (short)h5; hi[6] = (short)h6; hi[7] = (short)h7;
  lo[0] = (short)f2bf(v0 - bf2f(h0)); lo[1] = (short)f2bf(v1 - bf2f(h1));
  lo[2] = (short)f2bf(v2 - bf2f(h2)); lo[3] = (short)f2bf(v3 - bf2f(h3));
  lo[4] = (short)f2bf(v4 - bf2f(h4)); lo[5] = (short)f2bf(v5 - bf2f(h5));
  lo[6] = (short)f2bf(v6 - bf2f(h6)); lo[7] = (short)f2bf(v7 - bf2f(h7));
}

__device__ __forceinline__ short8 hi8(float4 u0, float4 u1) {
  short8 h;
  h[0] = (short)f2bf(u0.x); h[1] = (short)f2bf(u0.y);
  h[2] = (short)f2bf(u0.z); h[3] = (short)f2bf(u0.w);
  h[4] = (short)f2bf(u1.x); h[5] = (short)f2bf(u1.y);
  h[6] = (short)f2bf(u1.z); h[7] = (short)f2bf(u1.w);
  return h;
}

// ---- atomic-free binned CSC build (packed arena) ---------------------------

__global__ void init_bc_kernel(int* __restrict__ bc, int NB) {
  int b = threadIdx.x;
  if (b < NB) bc[b * 16] = b * BCAP;
}

__global__ __launch_bounds__(1024) void bin_edges_kernel(
    const int* __restrict__ src, const int* __restrict__ dst, int* __restrict__ bc,
    uint* __restrict__ arena, int E) {
  __shared__ int cnt[128], base[128];
  for (long chunk = (long)blockIdx.x * 4096; chunk < E; chunk += (long)gridDim.x * 4096) {
    if (threadIdx.x < 128) cnt[threadIdx.x] = 0;
    __syncthreads();
    uint v[4];
    int b[4], r[4];
#pragma unroll
    for (int u = 0; u < 4; ++u) {
      long e = chunk + threadIdx.x + u * 1024;
      if (e < E) {
        int s = src[e];
        int d = dst[e];
        b[u] = d >> BBITS;
        v[u] = ((uint)s << BBITS) | (uint)(d & BMASK);
        r[u] = atomicAdd(&cnt[b[u]], 1);
      }
    }
    __syncthreads();
    if (threadIdx.x < 128)
      base[threadIdx.x] = cnt[threadIdx.x] ? atomicAdd(&bc[threadIdx.x * 16], cnt[threadIdx.x]) : 0;
    __syncthreads();
#pragma unroll
    for (int u = 0; u < 4; ++u) {
      long e = chunk + threadIdx.x + u * 1024;
      if (e < E) arena[base[b[u]] + r[u]] = v[u];
    }
    __syncthreads();
  }
}

__global__ __launch_bounds__(1024) void bucket_count_kernel(
    const uint* __restrict__ arena, const int* __restrict__ bc,
    int* __restrict__ deg, int N) {
  __shared__ int hist[1 << BBITS];
  int b = blockIdx.x;
  int lo = b << BBITS;
  int hi = min(lo + (1 << BBITS), N);
  hist[threadIdx.x] = 0;
  __syncthreads();
  int cnt = bc[b * 16] - b * BCAP;
  const uint* ad = arena + (size_t)b * BCAP;
  for (int i = threadIdx.x; i < cnt; i += 1024) atomicAdd(&hist[ad[i] & BMASK], 1);
  __syncthreads();
  if (lo + (int)threadIdx.x < hi) deg[lo + threadIdx.x] = hist[threadIdx.x];
}

__global__ __launch_bounds__(1024) void bucket_scatter_kernel(
    const uint* __restrict__ arena, const int* __restrict__ bc,
    const int* __restrict__ rp, int* __restrict__ col, int N) {
  __shared__ int cur[1 << BBITS];
  int b = blockIdx.x;
  int lo = b << BBITS;
  int hi = min(lo + (1 << BBITS), N);
  if (lo + (int)threadIdx.x < hi) cur[threadIdx.x] = rp[lo + threadIdx.x];
  __syncthreads();
  int cnt = bc[b * 16] - b * BCAP;
  const uint* ad = arena + (size_t)b * BCAP;
  for (int i = threadIdx.x; i < cnt; i += 1024) {
    uint v = ad[i];
    int pos = atomicAdd(&cur[v & BMASK], 1);
    col[pos] = (int)(v >> BBITS);
  }
}

// ---- scan -----------------------------------------------------------------
__global__ void scan_blocksums(const int* __restrict__ deg, int* __restrict__ bsum, int N) {
  __shared__ int red[256];
  int i = blockIdx.x * 256 + threadIdx.x;
  red[threadIdx.x] = (i < N) ? deg[i] : 0;
  __syncthreads();
  for (int off = 128; off > 0; off >>= 1) {
    if (threadIdx.x < off) red[threadIdx.x] += red[threadIdx.x + off];
    __syncthreads();
  }
  if (threadIdx.x == 0) bsum[blockIdx.x] = red[0];
}

__global__ void scan_bsum(const int* __restrict__ bsum, int* __restrict__ boff,
                          int* __restrict__ rp_last, int B) {
  __shared__ int tmp[1024];
  int t = threadIdx.x;
  int v = (t < B) ? bsum[t] : 0;
  tmp[t] = v;
  __syncthreads();
  for (int off = 1; off < 1024; off <<= 1) {
    int u = (t >= off) ? tmp[t - off] : 0;
    __syncthreads();
    tmp[t] += u;
    __syncthreads();
  }
  if (t < B) boff[t] = tmp[t] - v;
  if (t == 1023) *rp_last = tmp[1023];
}

__global__ void scan_final(const int* __restrict__ deg, const int* __restrict__ boff,
                           int* __restrict__ rp, int N) {
  __shared__ int tmp[256];
  int i = blockIdx.x * 256 + threadIdx.x;
  int v = (i < N) ? deg[i] : 0;
  tmp[threadIdx.x] = v;
  __syncthreads();
  for (int off = 1; off < 256; off <<= 1) {
    int u = (threadIdx.x >= off) ? tmp[threadIdx.x - off] : 0;
    __syncthreads();
    tmp[threadIdx.x] += u;
    __syncthreads();
  }
  if (i < N) rp[i] = boff[blockIdx.x] + tmp[threadIdx.x] - v;
}

__global__ void graph_bounds_kernel(const int* __restrict__ batch, int* __restrict__ gs,
                                    int N, int G) {
  int n = blockIdx.x * 256 + threadIdx.x;
  if (n >= N) return;
  int b = batch[n];
  int bp = (n == 0) ? -1 : batch[n - 1];
  for (int g = bp + 1; g <= b; ++g) gs[g] = n;
  if (n == N - 1)
    for (int g = b + 1; g <= G; ++g) gs[g] = N;
}

// Prepack W1/W2 into MFMA B-fragment order, split hi/lo bf16.
__global__ void prepack_w_kernel(const float* __restrict__ W1_rest,
                                 const float* __restrict__ W2, ushort* __restrict__ wp) {
  int l = blockIdx.x >> 1, g = blockIdx.x & 1;
  const float* W;
  if (g == 0) {
    if (l == 0) return;
    W = W1_rest + (size_t)(l - 1) * 4096;
  } else {
    W = W2 + (size_t)l * 4096;
  }
  ushort* out = wp + (size_t)(l * 2 + g) * 8192;
  for (int idx = threadIdx.x; idx < 4096; idx += blockDim.x) {
    int j = idx & 7, lane = (idx >> 3) & 63, ks = (idx >> 9) & 1, nt = (idx >> 10) & 3;
    int k = ks * 32 + (lane >> 4) * 8 + j;
    int n = nt * 16 + (lane & 15);
    float w = W[k * 64 + n];
    ushort hi = f2bf(w);
    ushort lo = f2bf(w - bf2f(hi));
    size_t base = (size_t)((nt * 2 + ks) * 2) * 512 + lane * 8 + j;
    out[base] = hi;
    out[base + 512] = lo;
  }
}

// ---------------------------------------------------------------------------
// Fused GIN layer: agg prologue (pipelined col, z into sbuf f32) +
// MFMA MLP + mean-pool. 128 nodes/block, 512 threads.
// ---------------------------------------------------------------------------
__global__ __launch_bounds__(512) void fused_layer_kernel(
    const ushort* __restrict__ hb, const float* __restrict__ z0,
    const float* __restrict__ W1f, ushort* __restrict__ hout,
    const int* __restrict__ rp, const int* __restrict__ col,
    const float* __restrict__ eps,
    const ushort* __restrict__ wp1, const ushort* __restrict__ wp2,
    const float* __restrict__ b1, const float* __restrict__ g1,
    const float* __restrict__ be1, const float* __restrict__ m1,
    const float* __restrict__ v1,
    const float* __restrict__ b2, const float* __restrict__ g2,
    const float* __restrict__ be2, const float* __restrict__ m2,
    const float* __restrict__ v2,
    const int* __restrict__ batch, float* __restrict__ pooled,
    int layer, int skip1, int N) {
  __shared__ float bnp[6][64];
  __shared__ float w1fl[64];
  __shared__ float sbuf[128][68];  // phase0: z rows; phase1: t rows; epilogue: h
  __shared__ int batchl[128];
  int tid = threadIdx.x;
  int blockbase = blockIdx.x * 128;
  if (tid < 64) {
    bnp[0][tid] = b1[tid];
    float s1 = g1[tid] * rsqrtf(v1[tid] + 1e-5f);
    bnp[1][tid] = s1;
    bnp[2][tid] = be1[tid] - m1[tid] * s1;
    bnp[3][tid] = b2[tid];
    float s2 = g2[tid] * rsqrtf(v2[tid] + 1e-5f);
    bnp[4][tid] = s2;
    bnp[5][tid] = be2[tid] - m2[tid] * s2;
    if (skip1) w1fl[tid] = W1f[tid];
  }
  if (tid < 128) batchl[tid] = (blockbase + tid < N) ? batch[blockbase + tid] : -1;
  __syncthreads();
  int wave = tid >> 6, lane = tid & 63;
  int q = lane >> 4, c = lane & 15;
  int base = blockbase + wave * 16;
  int srow = wave * 16;  // this wave's strip base row in sbuf

  short8 ahi0, alo0, ahi1, alo1;
  if (!skip1) {
    // ---- agg prologue: this wave's 16 nodes, 4 quads of
    // 4 nodes x (2 edge-slots x 8 chunk-lanes). z (f32) -> own sbuf rows.
    // col loads software-pipelined one granule ahead; hv self-term load
    // hoisted above the edge loop.
    int ni = lane >> 4;          // node within quad (== q)
    int s = (lane >> 3) & 1;     // edge slot
    int r = lane & 7;            // 16B chunk
    float ep = 1.0f + eps[layer];
    for (int qq = 0; qq < 4; ++qq) {
      int node = base + qq * 4 + ni;
      bool valid = node < N;
      int nn = valid ? node : (N - 1);
      int beg = rp[nn];
      int end = valid ? rp[nn + 1] : beg;
      float a[8] = {0.f, 0.f, 0.f, 0.f, 0.f, 0.f, 0.f, 0.f};
      // self-term load issued early: hides under the edge loop.
      uint4 hv = ((const uint4*)(hb + (long)nn * 64))[r];
      int e = beg + s;
      int cc[4];
      float mm[4];
#pragma unroll
      for (int k = 0; k < 4; ++k) {
        int ec = e + 2 * k;
        bool ok = ec < end;
        mm[k] = ok ? 1.0f : 0.0f;
        cc[k] = __builtin_nontemporal_load(col + (ok ? ec : 0));
      }
      while (e < end) {
        uint4 ww[4];
#pragma unroll
        for (int k = 0; k < 4; ++k)
          ww[k] = ((const uint4*)(hb + (long)cc[k] * 64))[r];
        int en = e + 8;
        int cn[4];
        float mn[4];
#pragma unroll
        for (int k = 0; k < 4; ++k) {
          int ec = en + 2 * k;
          bool ok = ec < end;
          mn[k] = ok ? 1.0f : 0.0f;
          cn[k] = __builtin_nontemporal_load(col + (ok ? ec : 0));
        }
#pragma unroll
        for (int k = 0; k < 4; ++k) {
          a[0] = fmaf(mm[k], bf_lo(ww[k].x), a[0]);
          a[1] = fmaf(mm[k], bf_hi(ww[k].x), a[1]);
          a[2] = fmaf(mm[k], bf_lo(ww[k].y), a[2]);
          a[3] = fmaf(mm[k], bf_hi(ww[k].y), a[3]);
          a[4] = fmaf(mm[k], bf_lo(ww[k].z), a[4]);
          a[5] = fmaf(mm[k], bf_hi(ww[k].z), a[5]);
          a[6] = fmaf(mm[k], bf_lo(ww[k].w), a[6]);
          a[7] = fmaf(mm[k], bf_hi(ww[k].w), a[7]);
        }
#pragma unroll
        for (int k = 0; k < 4; ++k) { cc[k] = cn[k]; mm[k] = mn[k]; }
        e = en;
      }
#pragma unroll
      for (int j = 0; j < 8; ++j) a[j] = slot_combine(a[j]);
      if (s == 0) {
        float v0 = fmaf(ep, bf_lo(hv.x), a[0]), v1 = fmaf(ep, bf_hi(hv.x), a[1]);
        float v2 = fmaf(ep, bf_lo(hv.y), a[2]), v3 = fmaf(ep, bf_hi(hv.y), a[3]);
        float v4 = fmaf(ep, bf_lo(hv.z), a[4]), v5 = fmaf(ep, bf_hi(hv.z), a[5]);
        float v6 = fmaf(ep, bf_lo(hv.w), a[6]), v7 = fmaf(ep, bf_hi(hv.w), a[7]);
        int row = srow + qq * 4 + ni;
        *(float4*)&sbuf[row][r * 8] = make_float4(v0, v1, v2, v3);
        *(float4*)&sbuf[row][r * 8 + 4] = make_float4(v4, v5, v6, v7);
      }
    }
    // ---- A-fragments from sbuf z rows (same-wave in-order LDS)
    {
      float4 u0 = *(const float4*)&sbuf[srow + c][q * 8];
      float4 u1 = *(const float4*)&sbuf[srow + c][q * 8 + 4];
      ahi0 = hi8(u0, u1);
      u0 = *(const float4*)&sbuf[srow + c][32 + q * 8];
      u1 = *(const float4*)&sbuf[srow + c][32 + q * 8 + 4];
      ahi1 = hi8(u0, u1);
    }
    floatx4 acc[4];
#pragma unroll
    for (int nt = 0; nt < 4; ++nt) acc[nt] = (floatx4){0.f, 0.f, 0.f, 0.f};
#pragma unroll
    for (int nt = 0; nt < 4; ++nt) {
#pragma unroll
      for (int ks = 0; ks < 2; ++ks) {
        const ushort* fb = wp1 + ((nt * 2 + ks) * 2) * 512 + lane * 8;
        short8 bh = *(const short8*)fb;
        short8 bl = *(const short8*)(fb + 512);
        short8 ah = ks ? ahi1 : ahi0;
        acc[nt] = __builtin_amdgcn_mfma_f32_16x16x32_bf16(ah, bh, acc[nt], 0, 0, 0);
        acc[nt] = __builtin_amdgcn_mfma_f32_16x16x32_bf16(ah, bl, acc[nt], 0, 0, 0);
      }
    }
#pragma unroll
    for (int nt = 0; nt < 4; ++nt) {
      int feat = nt * 16 + c;
      float s1 = bnp[1][feat], o1 = bnp[2][feat], bb = bnp[0][feat];
#pragma unroll
      for (int r2 = 0; r2 < 4; ++r2) {
        float y = fmaxf(acc[nt][r2] + bb, 0.f);
        sbuf[srow + q * 4 + r2][feat] = fmaf(y, s1, o1);
      }
    }
    float4 u0 = *(const float4*)&sbuf[srow + c][q * 8];
    float4 u1 = *(const float4*)&sbuf[srow + c][q * 8 + 4];
    split8(u0, u1, ahi0, alo0);
    u0 = *(const float4*)&sbuf[srow + c][32 + q * 8];
    u1 = *(const float4*)&sbuf[srow + c][32 + q * 8 + 4];
    split8(u0, u1, ahi1, alo1);
  } else {
    long row = base + c;
    if (row >= N) row = N - 1;
    float zv = z0[row];
    float4 t00, t01, t10, t11;
    {
      float tv[8];
#pragma unroll
      for (int j = 0; j < 8; ++j) {
        int k = q * 8 + j;
        float y = fmaxf(fmaf(zv, w1fl[k], bnp[0][k]), 0.f);
        tv[j] = fmaf(y, bnp[1][k], bnp[2][k]);
      }
      t00 = make_float4(tv[0], tv[1], tv[2], tv[3]);
      t01 = make_float4(tv[4], tv[5], tv[6], tv[7]);
#pragma unroll
      for (int j = 0; j < 8; ++j) {
        int k = 32 + q * 8 + j;
        float y = fmaxf(fmaf(zv, w1fl[k], bnp[0][k]), 0.f);
        tv[j] = fmaf(y, bnp[1][k], bnp[2][k]);
      }
      t10 = make_float4(tv[0], tv[1], tv[2], tv[3]);
      t11 = make_float4(tv[4], tv[5], tv[6], tv[7]);
    }
    split8(t00, t01, ahi0, alo0);
    split8(t10, t11, ahi1, alo1);
  }

  // GEMM2: 3-term
  floatx4 acc2[4];
#pragma unroll
  for (int nt = 0; nt < 4; ++nt) acc2[nt] = (floatx4){0.f, 0.f, 0.f, 0.f};
#pragma unroll
  for (int nt = 0; nt < 4; ++nt) {
#pragma unroll
    for (int ks = 0; ks < 2; ++ks) {
      const ushort* fb = wp2 + ((nt * 2 + ks) * 2) * 512 + lane * 8;
      short8 bh = *(const short8*)fb;
      short8 bl = *(const short8*)(fb + 512);
      short8 ah = ks ? ahi1 : ahi0;
      short8 al = ks ? alo1 : alo0;
      acc2[nt] = __builtin_amdgcn_mfma_f32_16x16x32_bf16(ah, bh, acc2[nt], 0, 0, 0);
      acc2[nt] = __builtin_amdgcn_mfma_f32_16x16x32_bf16(al, bh, acc2[nt], 0, 0, 0);
      acc2[nt] = __builtin_amdgcn_mfma_f32_16x16x32_bf16(ah, bl, acc2[nt], 0, 0, 0);
    }
  }

  // bn2 -> stage vals in sbuf (wave-local rows)
#pragma unroll
  for (int nt = 0; nt < 4; ++nt) {
    int feat = nt * 16 + c;
    float s2 = bnp[4][feat], o2 = bnp[5][feat], bb = bnp[3][feat];
#pragma unroll
    for (int r2 = 0; r2 < 4; ++r2) {
      int node = base + q * 4 + r2;
      float val = 0.f;
      if (node < N) {
        float y = fmaxf(acc2[nt][r2] + bb, 0.f);
        val = fmaf(y, s2, o2);
      }
      sbuf[srow + q * 4 + r2][feat] = val;
    }
  }
  __syncthreads();

  // vectorized h stores: 128 rows x 8 chunks of 16B; 2 chunks/thread
#pragma unroll
  for (int it = 0; it < 2; ++it) {
    int chunk = tid + it * 512;
    int row = chunk >> 3, c8 = chunk & 7;
    int node = blockbase + row;
    if (node < N) {
      const float* sp = &sbuf[row][c8 * 8];
      uintx4 w;
      w.x = pack_bf16(sp[0], sp[1]);
      w.y = pack_bf16(sp[2], sp[3]);
      w.z = pack_bf16(sp[4], sp[5]);
      w.w = pack_bf16(sp[6], sp[7]);
      *(uintx4*)(hout + (long)node * 64 + c8 * 8) = w;
    }
  }

  // parallel segment sums: 256 threads = feat(64) x quarter(4), 32 rows each
  if (tid < 256) {
    int j = tid & 63;
    int quarter = tid >> 6;
    int nvalid = N - blockbase;
    if (nvalid > 128) nvalid = 128;
    int i = quarter * 32;
    int iend = i + 32;
    if (iend > nvalid) iend = nvalid;
    while (i < iend) {
      int g = batchl[i];
      float s = 0.f;
      while (i < iend && batchl[i] == g) { s += sbuf[i][j]; ++i; }
      atomicAdd(&pooled[(size_t)g * 512 + layer * 64 + j], s);
    }
  }
}

__global__ void z0_kernel(const float* __restrict__ x, const int* __restrict__ rp,
                          const int* __restrict__ col, const float* __restrict__ eps,
                          float* __restrict__ z0, int N) {
  int n = blockIdx.x * blockDim.x + threadIdx.x;
  if (n >= N) return;
  int beg = rp[n], end = rp[n + 1];
  float a = 0.f;
  for (int e = beg; e < end; ++e) a += x[col[e]];
  z0[n] = fmaf(1.0f + eps[0], x[n], a);
}

__global__ __launch_bounds__(64) void final_kernel(
    const float* __restrict__ pooled, const int* __restrict__ gs,
    const float* __restrict__ lin1_w, const float* __restrict__ lin1_b,
    const float* __restrict__ lin2_w, const float* __restrict__ lin2_b,
    float* __restrict__ out, int G) {
  int g = blockIdx.x;
  int j = threadIdx.x;
  float inv = 1.0f / fmaxf((float)(gs[g + 1] - gs[g]), 1.0f);
  __shared__ float p[512];
  for (int t = j; t < 512; t += 64) p[t] = pooled[(long)g * 512 + t] * inv;
  __syncthreads();
  float a0 = lin1_b[j], a1 = 0.f, a2 = 0.f, a3 = 0.f;
  for (int k = 0; k < 512; k += 4) {
    a0 = fmaf(p[k + 0], lin1_w[(k + 0) * 64 + j], a0);
    a1 = fmaf(p[k + 1], lin1_w[(k + 1) * 64 + j], a1);
    a2 = fmaf(p[k + 2], lin1_w[(k + 2) * 64 + j], a2);
    a3 = fmaf(p[k + 3], lin1_w[(k + 3) * 64 + j], a3);
  }
  float hv = fmaxf((a0 + a1) + (a2 + a3), 0.f);
  __shared__ float hb[64];
  hb[j] = hv;
  __syncthreads();
  __shared__ float lg[3];
  if (j < 3) {
    float a = lin2_b[j];
#pragma unroll
    for (int k = 0; k < 64; ++k) a = fmaf(hb[k], lin2_w[k * 3 + j], a);
    lg[j] = a;
  }
  __syncthreads();
  if (j < 3) {
    float mx = fmaxf(fmaxf(lg[0], lg[1]), lg[2]);
    float lse = mx + logf(expf(lg[0] - mx) + expf(lg[1] - mx) + expf(lg[2] - mx));
    out[g * 3 + j] = lg[j] - lse;
  }
}

extern "C" void kernel_launch(void* const* d_in, const int* in_sizes, int n_in,
                              void* d_out, int out_size, void* d_ws, size_t ws_size,
                              hipStream_t stream) {
  const float* x        = (const float*)d_in[0];
  const int*   edge     = (const int*)d_in[1];
  const int*   batch    = (const int*)d_in[2];
  const float* eps      = (const float*)d_in[4];
  const float* W1_first = (const float*)d_in[5];
  const float* W1_rest  = (const float*)d_in[6];
  const float* b1       = (const float*)d_in[7];
  const float* g1       = (const float*)d_in[8];
  const float* be1      = (const float*)d_in[9];
  const float* m1       = (const float*)d_in[10];
  const float* v1       = (const float*)d_in[11];
  const float* W2       = (const float*)d_in[12];
  const float* b2       = (const float*)d_in[13];
  const float* g2       = (const float*)d_in[14];
  const float* be2      = (const float*)d_in[15];
  const float* m2       = (const float*)d_in[16];
  const float* v2       = (const float*)d_in[17];
  const float* lin1_w   = (const float*)d_in[18];
  const float* lin1_b   = (const float*)d_in[19];
  const float* lin2_w   = (const float*)d_in[20];
  const float* lin2_b   = (const float*)d_in[21];

  int N = in_sizes[0];
  int E = in_sizes[1] / 2;
  int G = out_size / 3;
  const int* esrc = edge;
  const int* edst = edge + E;
  int NB = (N + (1 << BBITS) - 1) >> BBITS;
  if (NB > 128) NB = 128;

  size_t off = 0;
  auto alloc = [&](size_t bytes) -> char* {
    char* p = (char*)d_ws + off;
    off += (bytes + 255) & ~(size_t)255;
    return p;
  };
  int SB = (N + 255) / 256;
  int*    deg    = (int*)alloc((size_t)N * 4);
  int*    rp     = (int*)alloc((size_t)(N + 1) * 4);
  int*    col    = (int*)alloc((size_t)E * 4);
  int*    bsum   = (int*)alloc((size_t)SB * 4);
  int*    boff   = (int*)alloc((size_t)SB * 4);
  int*    bc     = (int*)alloc((size_t)128 * 16 * 4);
  uint*   arena  = (uint*)alloc((size_t)NB * BCAP * 4);
  int*    gs     = (int*)alloc((size_t)(G + 1) * 4);
  ushort* wpack  = (ushort*)alloc((size_t)16 * 8192 * 2);
  float*  z0buf  = (float*)alloc((size_t)N * 4);
  ushort* hA     = (ushort*)alloc((size_t)N * 64 * 2);
  ushort* hB     = (ushort*)alloc((size_t)N * 64 * 2);
  float*  pooled = (float*)alloc((size_t)G * 512 * 4);
  (void)ws_size;

  // atomic-free binned CSC build (packed arena)
  init_bc_kernel<<<1, 128, 0, stream>>>(bc, NB);
  int ebA = (E + 4095) / 4096;
  bin_edges_kernel<<<ebA, 1024, 0, stream>>>(esrc, edst, bc, arena, E);
  bucket_count_kernel<<<NB, 1024, 0, stream>>>(arena, bc, deg, N);
  scan_blocksums<<<SB, 256, 0, stream>>>(deg, bsum, N);
  scan_bsum<<<1, 1024, 0, stream>>>(bsum, boff, rp + N, SB);
  scan_final<<<SB, 256, 0, stream>>>(deg, boff, rp, N);
  bucket_scatter_kernel<<<NB, 1024, 0, stream>>>(arena, bc, rp, col, N);

  graph_bounds_kernel<<<SB, 256, 0, stream>>>(batch, gs, N, G);
  prepack_w_kernel<<<16, 256, 0, stream>>>(W1_rest, W2, wpack);
  (void)hipMemsetAsync(pooled, 0, (size_t)G * 512 * 4, stream);

  int nb = (N + 127) / 128;
  z0_kernel<<<SB, 256, 0, stream>>>(x, rp, col, eps, z0buf, N);
  fused_layer_kernel<<<nb, 512, 0, stream>>>(hA, z0buf, W1_first, hA,
      rp, col, eps, wpack, wpack + 8192,
      b1, g1, be1, m1, v1, b2, g2, be2, m2, v2, batch, pooled, 0, 1, N);

  ushort* hin = hA;
  ushort* hout = hB;
  for (int i = 1; i < 8; ++i) {
    fused_layer_kernel<<<nb, 512, 0, stream>>>(hin, z0buf, W1_first, hout,
        rp, col, eps,
        wpack + (size_t)(2 * i) * 8192, wpack + (size_t)(2 * i + 1) * 8192,
        b1 + i * 64, g1 + i * 64, be1 + i * 64, m1 + i * 64, v1 + i * 64,
        b2 + i * 64, g2 + i * 64, be2 + i * 64, m2 + i * 64, v2 + i * 64,
        batch, pooled, i, 0, N);
    ushort* t = hin; hin = hout; hout = t;
  }
  final_kernel<<<G, 64, 0, stream>>>(pooled, gs, lin1_w, lin1_b,
                                     lin2_w, lin2_b, (float*)d_out, G);
}

// Round 10
// 517.568 us; speedup vs baseline: 9.6528x; 1.0797x over previous
//
#include <hip/hip_runtime.h>
#include <hip/hip_bf16.h>
#include <math.h>

// ---------------------------------------------------------------------------
// GIN + JumpingKnowledge(cat) + mean-pool + 2-layer head, eval mode.
// R26 = R19 exact revert (best verified: 517.7us).
// Session evidence that R19 is the floor for this decomposition:
//  - agg restructures: R20 (64-node/8-deep, 567us), R21 (LDS-atomic edge-
//    parallel, 4996us), R22 (quad-pair interleave, 570us), R23 (manual col
//    pipeline, 559us) -- ALL regressed vs R19's 49.3us/layer. The gather
//    is latency/fabric-bound (FETCH ~86MB/layer ~ compulsory floor,
//    ~2TB/s random-line rate), not schedulable from source.
//  - launch-boundary recovery: R24 cooperative grid.sync -> WRONG ANSWERS
//    under graph capture; R25 hand-rolled spin barrier -> container HANG.
//    Both grid-wide-sync routes dead in this harness.
// Structure: fused layer kernel = agg prologue (per-wave 16-node gather,
// quad x (2 edge-slots x 8 chunk-lanes), xor-8 slot combine) -> z f32 in
// sbuf -> split-bf16 MFMA MLP (exact-fp32-emulating 2/3-term products) ->
// bn -> vectorized h stores + fused mean-pool. 512thr/128 nodes.
// ---------------------------------------------------------------------------

typedef unsigned int uint;
typedef unsigned short ushort;
typedef __attribute__((ext_vector_type(8))) short short8;
typedef __attribute__((ext_vector_type(4))) float floatx4;
typedef __attribute__((ext_vector_type(4))) uint uintx4;

#define BBITS 10                 // 1024 nodes per bucket
#define BCAP 20480               // arena capacity per bucket
#define BMASK ((1 << BBITS) - 1)

__device__ __forceinline__ float bf_lo(uint w) { return __uint_as_float(w << 16); }
__device__ __forceinline__ float bf_hi(uint w) { return __uint_as_float(w & 0xffff0000u); }

__device__ __forceinline__ ushort f2bf(float x) {
  __hip_bfloat16 h = __float2bfloat16(x);
  return *(ushort*)&h;
}
__device__ __forceinline__ float bf2f(ushort u) { return __uint_as_float((uint)u << 16); }

__device__ __forceinline__ uint pack_bf16(float a, float b) {
  return (uint)f2bf(a) | ((uint)f2bf(b) << 16);
}

// combine the two edge-slots (lane ^ 8) of a 16-lane node-row: one level.
__device__ __forceinline__ float slot_combine(float v) {
  return v + __shfl_xor(v, 8, 64);
}

__device__ __forceinline__ void split8(float4 u0, float4 u1, short8& hi, short8& lo) {
  float v0 = u0.x, v1 = u0.y, v2 = u0.z, v3 = u0.w;
  float v4 = u1.x, v5 = u1.y, v6 = u1.z, v7 = u1.w;
  ushort h0 = f2bf(v0), h1 = f2bf(v1), h2 = f2bf(v2), h3 = f2bf(v3);
  ushort h4 = f2bf(v4), h5 = f2bf(v5), h6 = f2bf(v6), h7 = f2bf(v7);
  hi[0] = (short)h0; hi[1] = (short)h1; hi[2] = (short)h2; hi[3] = (short)h3;
  hi[4] = (short)h4; hi[5] = (short)h5; hi[6] = (short)h6; hi[7] = (short)h7;
  lo[0] = (short)f2bf(v0 - bf2f(h0)); lo[1] = (short)f2bf(v1 - bf2f(h1));
  lo[2] = (short)f2bf(v2 - bf2f(h2)); lo[3] = (short)f2bf(v3 - bf2f(h3));
  lo[4] = (short)f2bf(v4 - bf2f(h4)); lo[5] = (short)f2bf(v5 - bf2f(h5));
  lo[6] = (short)f2bf(v6 - bf2f(h6)); lo[7] = (short)f2bf(v7 - bf2f(h7));
}

__device__ __forceinline__ short8 hi8(float4 u0, float4 u1) {
  short8 h;
  h[0] = (short)f2bf(u0.x); h[1] = (short)f2bf(u0.y);
  h[2] = (short)f2bf(u0.z); h[3] = (short)f2bf(u0.w);
  h[4] = (short)f2bf(u1.x); h[5] = (short)f2bf(u1.y);
  h[6] = (short)f2bf(u1.z); h[7] = (short)f2bf(u1.w);
  return h;
}

// ---- atomic-free binned CSC build (packed arena) ---------------------------

__global__ void init_bc_kernel(int* __restrict__ bc, int NB) {
  int b = threadIdx.x;
  if (b < NB) bc[b * 16] = b * BCAP;
}

__global__ __launch_bounds__(1024) void bin_edges_kernel(
    const int* __restrict__ src, const int* __restrict__ dst, int* __restrict__ bc,
    uint* __restrict__ arena, int E) {
  __shared__ int cnt[128], base[128];
  for (long chunk = (long)blockIdx.x * 4096; chunk < E; chunk += (long)gridDim.x * 4096) {
    if (threadIdx.x < 128) cnt[threadIdx.x] = 0;
    __syncthreads();
    uint v[4];
    int b[4], r[4];
#pragma unroll
    for (int u = 0; u < 4; ++u) {
      long e = chunk + threadIdx.x + u * 1024;
      if (e < E) {
        int s = src[e];
        int d = dst[e];
        b[u] = d >> BBITS;
        v[u] = ((uint)s << BBITS) | (uint)(d & BMASK);
        r[u] = atomicAdd(&cnt[b[u]], 1);
      }
    }
    __syncthreads();
    if (threadIdx.x < 128)
      base[threadIdx.x] = cnt[threadIdx.x] ? atomicAdd(&bc[threadIdx.x * 16], cnt[threadIdx.x]) : 0;
    __syncthreads();
#pragma unroll
    for (int u = 0; u < 4; ++u) {
      long e = chunk + threadIdx.x + u * 1024;
      if (e < E) arena[base[b[u]] + r[u]] = v[u];
    }
    __syncthreads();
  }
}

__global__ __launch_bounds__(1024) void bucket_count_kernel(
    const uint* __restrict__ arena, const int* __restrict__ bc,
    int* __restrict__ deg, int N) {
  __shared__ int hist[1 << BBITS];
  int b = blockIdx.x;
  int lo = b << BBITS;
  int hi = min(lo + (1 << BBITS), N);
  hist[threadIdx.x] = 0;
  __syncthreads();
  int cnt = bc[b * 16] - b * BCAP;
  const uint* ad = arena + (size_t)b * BCAP;
  for (int i = threadIdx.x; i < cnt; i += 1024) atomicAdd(&hist[ad[i] & BMASK], 1);
  __syncthreads();
  if (lo + (int)threadIdx.x < hi) deg[lo + threadIdx.x] = hist[threadIdx.x];
}

__global__ __launch_bounds__(1024) void bucket_scatter_kernel(
    const uint* __restrict__ arena, const int* __restrict__ bc,
    const int* __restrict__ rp, int* __restrict__ col, int N) {
  __shared__ int cur[1 << BBITS];
  int b = blockIdx.x;
  int lo = b << BBITS;
  int hi = min(lo + (1 << BBITS), N);
  if (lo + (int)threadIdx.x < hi) cur[threadIdx.x] = rp[lo + threadIdx.x];
  __syncthreads();
  int cnt = bc[b * 16] - b * BCAP;
  const uint* ad = arena + (size_t)b * BCAP;
  for (int i = threadIdx.x; i < cnt; i += 1024) {
    uint v = ad[i];
    int pos = atomicAdd(&cur[v & BMASK], 1);
    col[pos] = (int)(v >> BBITS);
  }
}

// ---- scan -----------------------------------------------------------------
__global__ void scan_blocksums(const int* __restrict__ deg, int* __restrict__ bsum, int N) {
  __shared__ int red[256];
  int i = blockIdx.x * 256 + threadIdx.x;
  red[threadIdx.x] = (i < N) ? deg[i] : 0;
  __syncthreads();
  for (int off = 128; off > 0; off >>= 1) {
    if (threadIdx.x < off) red[threadIdx.x] += red[threadIdx.x + off];
    __syncthreads();
  }
  if (threadIdx.x == 0) bsum[blockIdx.x] = red[0];
}

__global__ void scan_bsum(const int* __restrict__ bsum, int* __restrict__ boff,
                          int* __restrict__ rp_last, int B) {
  __shared__ int tmp[1024];
  int t = threadIdx.x;
  int v = (t < B) ? bsum[t] : 0;
  tmp[t] = v;
  __syncthreads();
  for (int off = 1; off < 1024; off <<= 1) {
    int u = (t >= off) ? tmp[t - off] : 0;
    __syncthreads();
    tmp[t] += u;
    __syncthreads();
  }
  if (t < B) boff[t] = tmp[t] - v;
  if (t == 1023) *rp_last = tmp[1023];
}

__global__ void scan_final(const int* __restrict__ deg, const int* __restrict__ boff,
                           int* __restrict__ rp, int N) {
  __shared__ int tmp[256];
  int i = blockIdx.x * 256 + threadIdx.x;
  int v = (i < N) ? deg[i] : 0;
  tmp[threadIdx.x] = v;
  __syncthreads();
  for (int off = 1; off < 256; off <<= 1) {
    int u = (threadIdx.x >= off) ? tmp[threadIdx.x - off] : 0;
    __syncthreads();
    tmp[threadIdx.x] += u;
    __syncthreads();
  }
  if (i < N) rp[i] = boff[blockIdx.x] + tmp[threadIdx.x] - v;
}

__global__ void graph_bounds_kernel(const int* __restrict__ batch, int* __restrict__ gs,
                                    int N, int G) {
  int n = blockIdx.x * 256 + threadIdx.x;
  if (n >= N) return;
  int b = batch[n];
  int bp = (n == 0) ? -1 : batch[n - 1];
  for (int g = bp + 1; g <= b; ++g) gs[g] = n;
  if (n == N - 1)
    for (int g = b + 1; g <= G; ++g) gs[g] = N;
}

// Prepack W1/W2 into MFMA B-fragment order, split hi/lo bf16.
__global__ void prepack_w_kernel(const float* __restrict__ W1_rest,
                                 const float* __restrict__ W2, ushort* __restrict__ wp) {
  int l = blockIdx.x >> 1, g = blockIdx.x & 1;
  const float* W;
  if (g == 0) {
    if (l == 0) return;
    W = W1_rest + (size_t)(l - 1) * 4096;
  } else {
    W = W2 + (size_t)l * 4096;
  }
  ushort* out = wp + (size_t)(l * 2 + g) * 8192;
  for (int idx = threadIdx.x; idx < 4096; idx += blockDim.x) {
    int j = idx & 7, lane = (idx >> 3) & 63, ks = (idx >> 9) & 1, nt = (idx >> 10) & 3;
    int k = ks * 32 + (lane >> 4) * 8 + j;
    int n = nt * 16 + (lane & 15);
    float w = W[k * 64 + n];
    ushort hi = f2bf(w);
    ushort lo = f2bf(w - bf2f(hi));
    size_t base = (size_t)((nt * 2 + ks) * 2) * 512 + lane * 8 + j;
    out[base] = hi;
    out[base + 512] = lo;
  }
}

// ---------------------------------------------------------------------------
// Fused GIN layer: agg prologue (z into sbuf, f32) + MFMA MLP + mean-pool.
// 128 nodes/block, 512 threads (8 waves x 16-node strip).
// ---------------------------------------------------------------------------
__global__ __launch_bounds__(512) void fused_layer_kernel(
    const ushort* __restrict__ hb, const float* __restrict__ z0,
    const float* __restrict__ W1f, ushort* __restrict__ hout,
    const int* __restrict__ rp, const int* __restrict__ col,
    const float* __restrict__ eps,
    const ushort* __restrict__ wp1, const ushort* __restrict__ wp2,
    const float* __restrict__ b1, const float* __restrict__ g1,
    const float* __restrict__ be1, const float* __restrict__ m1,
    const float* __restrict__ v1,
    const float* __restrict__ b2, const float* __restrict__ g2,
    const float* __restrict__ be2, const float* __restrict__ m2,
    const float* __restrict__ v2,
    const int* __restrict__ batch, float* __restrict__ pooled,
    int layer, int skip1, int N) {
  __shared__ float bnp[6][64];
  __shared__ float w1fl[64];
  __shared__ float sbuf[128][68];  // phase0: z rows; phase1: t rows; epilogue: h
  __shared__ int batchl[128];
  int tid = threadIdx.x;
  int blockbase = blockIdx.x * 128;
  if (tid < 64) {
    bnp[0][tid] = b1[tid];
    float s1 = g1[tid] * rsqrtf(v1[tid] + 1e-5f);
    bnp[1][tid] = s1;
    bnp[2][tid] = be1[tid] - m1[tid] * s1;
    bnp[3][tid] = b2[tid];
    float s2 = g2[tid] * rsqrtf(v2[tid] + 1e-5f);
    bnp[4][tid] = s2;
    bnp[5][tid] = be2[tid] - m2[tid] * s2;
    if (skip1) w1fl[tid] = W1f[tid];
  }
  if (tid < 128) batchl[tid] = (blockbase + tid < N) ? batch[blockbase + tid] : -1;
  __syncthreads();
  int wave = tid >> 6, lane = tid & 63;
  int q = lane >> 4, c = lane & 15;
  int base = blockbase + wave * 16;
  int srow = wave * 16;  // this wave's strip base row in sbuf

  short8 ahi0, alo0, ahi1, alo1;
  if (!skip1) {
    // ---- agg prologue: this wave's 16 nodes, 4 quads of
    // 4 nodes x (2 edge-slots x 8 chunk-lanes). z (f32) -> own sbuf rows.
    int ni = lane >> 4;          // node within quad (== q)
    int s = (lane >> 3) & 1;     // edge slot
    int r = lane & 7;            // 16B chunk
    float ep = 1.0f + eps[layer];
    for (int qq = 0; qq < 4; ++qq) {
      int node = base + qq * 4 + ni;
      bool valid = node < N;
      int nn = valid ? node : (N - 1);
      int beg = rp[nn];
      int end = valid ? rp[nn + 1] : beg;
      float a[8] = {0.f, 0.f, 0.f, 0.f, 0.f, 0.f, 0.f, 0.f};
      int e = beg + s;
      while (e < end) {
        int e1 = (e + 2 < end) ? (e + 2) : e;
        int e2 = (e + 4 < end) ? (e + 4) : e;
        int e3 = (e + 6 < end) ? (e + 6) : e;
        float m1v = (e + 2 < end) ? 1.0f : 0.0f;
        float m2v = (e + 4 < end) ? 1.0f : 0.0f;
        float m3v = (e + 6 < end) ? 1.0f : 0.0f;
        int c0 = __builtin_nontemporal_load(col + e);
        int c1 = __builtin_nontemporal_load(col + e1);
        int c2 = __builtin_nontemporal_load(col + e2);
        int c3 = __builtin_nontemporal_load(col + e3);
        uint4 w0 = ((const uint4*)(hb + (long)c0 * 64))[r];
        uint4 w1 = ((const uint4*)(hb + (long)c1 * 64))[r];
        uint4 w2 = ((const uint4*)(hb + (long)c2 * 64))[r];
        uint4 w3 = ((const uint4*)(hb + (long)c3 * 64))[r];
        a[0] += bf_lo(w0.x); a[1] += bf_hi(w0.x);
        a[2] += bf_lo(w0.y); a[3] += bf_hi(w0.y);
        a[4] += bf_lo(w0.z); a[5] += bf_hi(w0.z);
        a[6] += bf_lo(w0.w); a[7] += bf_hi(w0.w);
        a[0] = fmaf(m1v, bf_lo(w1.x), a[0]); a[1] = fmaf(m1v, bf_hi(w1.x), a[1]);
        a[2] = fmaf(m1v, bf_lo(w1.y), a[2]); a[3] = fmaf(m1v, bf_hi(w1.y), a[3]);
        a[4] = fmaf(m1v, bf_lo(w1.z), a[4]); a[5] = fmaf(m1v, bf_hi(w1.z), a[5]);
        a[6] = fmaf(m1v, bf_lo(w1.w), a[6]); a[7] = fmaf(m1v, bf_hi(w1.w), a[7]);
        a[0] = fmaf(m2v, bf_lo(w2.x), a[0]); a[1] = fmaf(m2v, bf_hi(w2.x), a[1]);
        a[2] = fmaf(m2v, bf_lo(w2.y), a[2]); a[3] = fmaf(m2v, bf_hi(w2.y), a[3]);
        a[4] = fmaf(m2v, bf_lo(w2.z), a[4]); a[5] = fmaf(m2v, bf_hi(w2.z), a[5]);
        a[6] = fmaf(m2v, bf_lo(w2.w), a[6]); a[7] = fmaf(m2v, bf_hi(w2.w), a[7]);
        a[0] = fmaf(m3v, bf_lo(w3.x), a[0]); a[1] = fmaf(m3v, bf_hi(w3.x), a[1]);
        a[2] = fmaf(m3v, bf_lo(w3.y), a[2]); a[3] = fmaf(m3v, bf_hi(w3.y), a[3]);
        a[4] = fmaf(m3v, bf_lo(w3.z), a[4]); a[5] = fmaf(m3v, bf_hi(w3.z), a[5]);
        a[6] = fmaf(m3v, bf_lo(w3.w), a[6]); a[7] = fmaf(m3v, bf_hi(w3.w), a[7]);
        e += 8;
      }
#pragma unroll
      for (int j = 0; j < 8; ++j) a[j] = slot_combine(a[j]);
      if (s == 0) {
        uint4 hv = ((const uint4*)(hb + (long)nn * 64))[r];
        float v0 = fmaf(ep, bf_lo(hv.x), a[0]), v1 = fmaf(ep, bf_hi(hv.x), a[1]);
        float v2 = fmaf(ep, bf_lo(hv.y), a[2]), v3 = fmaf(ep, bf_hi(hv.y), a[3]);
        float v4 = fmaf(ep, bf_lo(hv.z), a[4]), v5 = fmaf(ep, bf_hi(hv.z), a[5]);
        float v6 = fmaf(ep, bf_lo(hv.w), a[6]), v7 = fmaf(ep, bf_hi(hv.w), a[7]);
        int row = srow + qq * 4 + ni;
        *(float4*)&sbuf[row][r * 8] = make_float4(v0, v1, v2, v3);
        *(float4*)&sbuf[row][r * 8 + 4] = make_float4(v4, v5, v6, v7);
      }
    }
    // ---- A-fragments from sbuf z rows (same-wave in-order LDS)
    {
      float4 u0 = *(const float4*)&sbuf[srow + c][q * 8];
      float4 u1 = *(const float4*)&sbuf[srow + c][q * 8 + 4];
      ahi0 = hi8(u0, u1);
      u0 = *(const float4*)&sbuf[srow + c][32 + q * 8];
      u1 = *(const float4*)&sbuf[srow + c][32 + q * 8 + 4];
      ahi1 = hi8(u0, u1);
    }
    floatx4 acc[4];
#pragma unroll
    for (int nt = 0; nt < 4; ++nt) acc[nt] = (floatx4){0.f, 0.f, 0.f, 0.f};
#pragma unroll
    for (int nt = 0; nt < 4; ++nt) {
#pragma unroll
      for (int ks = 0; ks < 2; ++ks) {
        const ushort* fb = wp1 + ((nt * 2 + ks) * 2) * 512 + lane * 8;
        short8 bh = *(const short8*)fb;
        short8 bl = *(const short8*)(fb + 512);
        short8 ah = ks ? ahi1 : ahi0;
        acc[nt] = __builtin_amdgcn_mfma_f32_16x16x32_bf16(ah, bh, acc[nt], 0, 0, 0);
        acc[nt] = __builtin_amdgcn_mfma_f32_16x16x32_bf16(ah, bl, acc[nt], 0, 0, 0);
      }
    }
#pragma unroll
    for (int nt = 0; nt < 4; ++nt) {
      int feat = nt * 16 + c;
      float s1 = bnp[1][feat], o1 = bnp[2][feat], bb = bnp[0][feat];
#pragma unroll
      for (int r2 = 0; r2 < 4; ++r2) {
        float y = fmaxf(acc[nt][r2] + bb, 0.f);
        sbuf[srow + q * 4 + r2][feat] = fmaf(y, s1, o1);
      }
    }
    float4 u0 = *(const float4*)&sbuf[srow + c][q * 8];
    float4 u1 = *(const float4*)&sbuf[srow + c][q * 8 + 4];
    split8(u0, u1, ahi0, alo0);
    u0 = *(const float4*)&sbuf[srow + c][32 + q * 8];
    u1 = *(const float4*)&sbuf[srow + c][32 + q * 8 + 4];
    split8(u0, u1, ahi1, alo1);
  } else {
    long row = base + c;
    if (row >= N) row = N - 1;
    float zv = z0[row];
    float4 t00, t01, t10, t11;
    {
      float tv[8];
#pragma unroll
      for (int j = 0; j < 8; ++j) {
        int k = q * 8 + j;
        float y = fmaxf(fmaf(zv, w1fl[k], bnp[0][k]), 0.f);
        tv[j] = fmaf(y, bnp[1][k], bnp[2][k]);
      }
      t00 = make_float4(tv[0], tv[1], tv[2], tv[3]);
      t01 = make_float4(tv[4], tv[5], tv[6], tv[7]);
#pragma unroll
      for (int j = 0; j < 8; ++j) {
        int k = 32 + q * 8 + j;
        float y = fmaxf(fmaf(zv, w1fl[k], bnp[0][k]), 0.f);
        tv[j] = fmaf(y, bnp[1][k], bnp[2][k]);
      }
      t10 = make_float4(tv[0], tv[1], tv[2], tv[3]);
      t11 = make_float4(tv[4], tv[5], tv[6], tv[7]);
    }
    split8(t00, t01, ahi0, alo0);
    split8(t10, t11, ahi1, alo1);
  }

  // GEMM2: 3-term
  floatx4 acc2[4];
#pragma unroll
  for (int nt = 0; nt < 4; ++nt) acc2[nt] = (floatx4){0.f, 0.f, 0.f, 0.f};
#pragma unroll
  for (int nt = 0; nt < 4; ++nt) {
#pragma unroll
    for (int ks = 0; ks < 2; ++ks) {
      const ushort* fb = wp2 + ((nt * 2 + ks) * 2) * 512 + lane * 8;
      short8 bh = *(const short8*)fb;
      short8 bl = *(const short8*)(fb + 512);
      short8 ah = ks ? ahi1 : ahi0;
      short8 al = ks ? alo1 : alo0;
      acc2[nt] = __builtin_amdgcn_mfma_f32_16x16x32_bf16(ah, bh, acc2[nt], 0, 0, 0);
      acc2[nt] = __builtin_amdgcn_mfma_f32_16x16x32_bf16(al, bh, acc2[nt], 0, 0, 0);
      acc2[nt] = __builtin_amdgcn_mfma_f32_16x16x32_bf16(ah, bl, acc2[nt], 0, 0, 0);
    }
  }

  // bn2 -> stage vals in sbuf (wave-local rows)
#pragma unroll
  for (int nt = 0; nt < 4; ++nt) {
    int feat = nt * 16 + c;
    float s2 = bnp[4][feat], o2 = bnp[5][feat], bb = bnp[3][feat];
#pragma unroll
    for (int r2 = 0; r2 < 4; ++r2) {
      int node = base + q * 4 + r2;
      float val = 0.f;
      if (node < N) {
        float y = fmaxf(acc2[nt][r2] + bb, 0.f);
        val = fmaf(y, s2, o2);
      }
      sbuf[srow + q * 4 + r2][feat] = val;
    }
  }
  __syncthreads();

  // vectorized h stores: 128 rows x 8 chunks of 16B; 2 chunks/thread
#pragma unroll
  for (int it = 0; it < 2; ++it) {
    int chunk = tid + it * 512;
    int row = chunk >> 3, c8 = chunk & 7;
    int node = blockbase + row;
    if (node < N) {
      const float* sp = &sbuf[row][c8 * 8];
      uintx4 w;
      w.x = pack_bf16(sp[0], sp[1]);
      w.y = pack_bf16(sp[2], sp[3]);
      w.z = pack_bf16(sp[4], sp[5]);
      w.w = pack_bf16(sp[6], sp[7]);
      *(uintx4*)(hout + (long)node * 64 + c8 * 8) = w;
    }
  }

  // parallel segment sums: 256 threads = feat(64) x quarter(4), 32 rows each
  if (tid < 256) {
    int j = tid & 63;
    int quarter = tid >> 6;
    int nvalid = N - blockbase;
    if (nvalid > 128) nvalid = 128;
    int i = quarter * 32;
    int iend = i + 32;
    if (iend > nvalid) iend = nvalid;
    while (i < iend) {
      int g = batchl[i];
      float s = 0.f;
      while (i < iend && batchl[i] == g) { s += sbuf[i][j]; ++i; }
      atomicAdd(&pooled[(size_t)g * 512 + layer * 64 + j], s);
    }
  }
}

__global__ void z0_kernel(const float* __restrict__ x, const int* __restrict__ rp,
                          const int* __restrict__ col, const float* __restrict__ eps,
                          float* __restrict__ z0, int N) {
  int n = blockIdx.x * blockDim.x + threadIdx.x;
  if (n >= N) return;
  int beg = rp[n], end = rp[n + 1];
  float a = 0.f;
  for (int e = beg; e < end; ++e) a += x[col[e]];
  z0[n] = fmaf(1.0f + eps[0], x[n], a);
}

__global__ __launch_bounds__(64) void final_kernel(
    const float* __restrict__ pooled, const int* __restrict__ gs,
    const float* __restrict__ lin1_w, const float* __restrict__ lin1_b,
    const float* __restrict__ lin2_w, const float* __restrict__ lin2_b,
    float* __restrict__ out, int G) {
  int g = blockIdx.x;
  int j = threadIdx.x;
  float inv = 1.0f / fmaxf((float)(gs[g + 1] - gs[g]), 1.0f);
  __shared__ float p[512];
  for (int t = j; t < 512; t += 64) p[t] = pooled[(long)g * 512 + t] * inv;
  __syncthreads();
  float a0 = lin1_b[j], a1 = 0.f, a2 = 0.f, a3 = 0.f;
  for (int k = 0; k < 512; k += 4) {
    a0 = fmaf(p[k + 0], lin1_w[(k + 0) * 64 + j], a0);
    a1 = fmaf(p[k + 1], lin1_w[(k + 1) * 64 + j], a1);
    a2 = fmaf(p[k + 2], lin1_w[(k + 2) * 64 + j], a2);
    a3 = fmaf(p[k + 3], lin1_w[(k + 3) * 64 + j], a3);
  }
  float hv = fmaxf((a0 + a1) + (a2 + a3), 0.f);
  __shared__ float hb[64];
  hb[j] = hv;
  __syncthreads();
  __shared__ float lg[3];
  if (j < 3) {
    float a = lin2_b[j];
#pragma unroll
    for (int k = 0; k < 64; ++k) a = fmaf(hb[k], lin2_w[k * 3 + j], a);
    lg[j] = a;
  }
  __syncthreads();
  if (j < 3) {
    float mx = fmaxf(fmaxf(lg[0], lg[1]), lg[2]);
    float lse = mx + logf(expf(lg[0] - mx) + expf(lg[1] - mx) + expf(lg[2] - mx));
    out[g * 3 + j] = lg[j] - lse;
  }
}

extern "C" void kernel_launch(void* const* d_in, const int* in_sizes, int n_in,
                              void* d_out, int out_size, void* d_ws, size_t ws_size,
                              hipStream_t stream) {
  const float* x        = (const float*)d_in[0];
  const int*   edge     = (const int*)d_in[1];
  const int*   batch    = (const int*)d_in[2];
  const float* eps      = (const float*)d_in[4];
  const float* W1_first = (const float*)d_in[5];
  const float* W1_rest  = (const float*)d_in[6];
  const float* b1       = (const float*)d_in[7];
  const float* g1       = (const float*)d_in[8];
  const float* be1      = (const float*)d_in[9];
  const float* m1       = (const float*)d_in[10];
  const float* v1       = (const float*)d_in[11];
  const float* W2       = (const float*)d_in[12];
  const float* b2       = (const float*)d_in[13];
  const float* g2       = (const float*)d_in[14];
  const float* be2      = (const float*)d_in[15];
  const float* m2       = (const float*)d_in[16];
  const float* v2       = (const float*)d_in[17];
  const float* lin1_w   = (const float*)d_in[18];
  const float* lin1_b   = (const float*)d_in[19];
  const float* lin2_w   = (const float*)d_in[20];
  const float* lin2_b   = (const float*)d_in[21];

  int N = in_sizes[0];
  int E = in_sizes[1] / 2;
  int G = out_size / 3;
  const int* esrc = edge;
  const int* edst = edge + E;
  int NB = (N + (1 << BBITS) - 1) >> BBITS;
  if (NB > 128) NB = 128;

  size_t off = 0;
  auto alloc = [&](size_t bytes) -> char* {
    char* p = (char*)d_ws + off;
    off += (bytes + 255) & ~(size_t)255;
    return p;
  };
  int SB = (N + 255) / 256;
  int*    deg    = (int*)alloc((size_t)N * 4);
  int*    rp     = (int*)alloc((size_t)(N + 1) * 4);
  int*    col    = (int*)alloc((size_t)E * 4);
  int*    bsum   = (int*)alloc((size_t)SB * 4);
  int*    boff   = (int*)alloc((size_t)SB * 4);
  int*    bc     = (int*)alloc((size_t)128 * 16 * 4);
  uint*   arena  = (uint*)alloc((size_t)NB * BCAP * 4);
  int*    gs     = (int*)alloc((size_t)(G + 1) * 4);
  ushort* wpack  = (ushort*)alloc((size_t)16 * 8192 * 2);
  float*  z0buf  = (float*)alloc((size_t)N * 4);
  ushort* hA     = (ushort*)alloc((size_t)N * 64 * 2);
  ushort* hB     = (ushort*)alloc((size_t)N * 64 * 2);
  float*  pooled = (float*)alloc((size_t)G * 512 * 4);
  (void)ws_size;

  // atomic-free binned CSC build (packed arena)
  init_bc_kernel<<<1, 128, 0, stream>>>(bc, NB);
  int ebA = (E + 4095) / 4096;
  bin_edges_kernel<<<ebA, 1024, 0, stream>>>(esrc, edst, bc, arena, E);
  bucket_count_kernel<<<NB, 1024, 0, stream>>>(arena, bc, deg, N);
  scan_blocksums<<<SB, 256, 0, stream>>>(deg, bsum, N);
  scan_bsum<<<1, 1024, 0, stream>>>(bsum, boff, rp + N, SB);
  scan_final<<<SB, 256, 0, stream>>>(deg, boff, rp, N);
  bucket_scatter_kernel<<<NB, 1024, 0, stream>>>(arena, bc, rp, col, N);

  graph_bounds_kernel<<<SB, 256, 0, stream>>>(batch, gs, N, G);
  prepack_w_kernel<<<16, 256, 0, stream>>>(W1_rest, W2, wpack);
  (void)hipMemsetAsync(pooled, 0, (size_t)G * 512 * 4, stream);

  int nb = (N + 127) / 128;
  z0_kernel<<<SB, 256, 0, stream>>>(x, rp, col, eps, z0buf, N);
  fused_layer_kernel<<<nb, 512, 0, stream>>>(hA, z0buf, W1_first, hA,
      rp, col, eps, wpack, wpack + 8192,
      b1, g1, be1, m1, v1, b2, g2, be2, m2, v2, batch, pooled, 0, 1, N);

  ushort* hin = hA;
  ushort* hout = hB;
  for (int i = 1; i < 8; ++i) {
    fused_layer_kernel<<<nb, 512, 0, stream>>>(hin, z0buf, W1_first, hout,
        rp, col, eps,
        wpack + (size_t)(2 * i) * 8192, wpack + (size_t)(2 * i + 1) * 8192,
        b1 + i * 64, g1 + i * 64, be1 + i * 64, m1 + i * 64, v1 + i * 64,
        b2 + i * 64, g2 + i * 64, be2 + i * 64, m2 + i * 64, v2 + i * 64,
        batch, pooled, i, 0, N);
    ushort* t = hin; hin = hout; hout = t;
  }
  final_kernel<<<G, 64, 0, stream>>>(pooled, gs, lin1_w, lin1_b,
                                     lin2_w, lin2_b, (float*)d_out, G);
}